// Round 2
// baseline (553.624 us; speedup 1.0000x reference)
//
#include <hip/hip_runtime.h>

typedef unsigned short u16;
typedef __attribute__((ext_vector_type(4))) unsigned int u32x4;
typedef __attribute__((ext_vector_type(4))) float f32x4;
typedef __attribute__((ext_vector_type(8))) short s16x8;

#define B_ 8
#define T_ 2048
#define C_ 1024
#define H_ 16
#define HS_ 64
#define CHUNK_ 256
#define NC_ 8

union U8 { u32x4 u; u16 h[8]; };

__device__ __forceinline__ float b2f(u16 v) {
    union { unsigned int i; float f; } c; c.i = ((unsigned int)v) << 16; return c.f;
}
__device__ __forceinline__ u16 f2b(float f) {
    union { float f; unsigned int i; } c; c.f = f;
    unsigned int i = c.i;
    return (u16)((i + 0x7FFFu + ((i >> 16) & 1u)) >> 16);  // RNE
}
__device__ __forceinline__ float sigmoidf_(float z) { return 1.f / (1.f + expf(-z)); }

// ---------------- K0: f32 -> bf16 weight conversion -------------------------
__global__ __launch_bounds__(256) void cvt_kernel(
    const float* __restrict__ src, u16* __restrict__ dst, int n8)
{
    int i = blockIdx.x * 256 + threadIdx.x;   // one thread per 8 elements
    if (i >= n8) return;
    f32x4 a = *reinterpret_cast<const f32x4*>(src + (size_t)i * 8);
    f32x4 b = *reinterpret_cast<const f32x4*>(src + (size_t)i * 8 + 4);
    U8 o;
    #pragma unroll
    for (int j = 0; j < 4; j++) { o.h[j] = f2b(a[j]); o.h[4 + j] = f2b(b[j]); }
    *reinterpret_cast<u32x4*>(dst + (size_t)i * 8) = o.u;
}

// ---------------- K1: volatility gate + time-shift + maa mix (f32 in, bf16 out)
__global__ __launch_bounds__(256) void mix_kernel(
    const float* __restrict__ x, const float* __restrict__ vol,
    const float* __restrict__ Wvol, const float* __restrict__ bvol,
    const float* __restrict__ mk, const float* __restrict__ mv, const float* __restrict__ mr,
    u16* __restrict__ xk, u16* __restrict__ xv, u16* __restrict__ xr)
{
    int idx = blockIdx.x * 256 + threadIdx.x;      // B*T*(C/8) threads
    int c0 = (idx & (C_/8 - 1)) * 8;
    int bt = idx >> 7;
    int t  = bt & (T_ - 1);
    size_t off = (size_t)bt * C_ + c0;

    float vc = vol[bt];
    bool hasp = (t > 0);
    float vp = hasp ? vol[bt - 1] : 0.f;

    f32x4 xa = *reinterpret_cast<const f32x4*>(x + off);
    f32x4 xb = *reinterpret_cast<const f32x4*>(x + off + 4);
    f32x4 pa = f32x4{0.f,0.f,0.f,0.f}, pb = f32x4{0.f,0.f,0.f,0.f};
    if (hasp) {
        pa = *reinterpret_cast<const f32x4*>(x + off - C_);
        pb = *reinterpret_cast<const f32x4*>(x + off - C_ + 4);
    }
    f32x4 wa = *reinterpret_cast<const f32x4*>(Wvol + c0);
    f32x4 wb = *reinterpret_cast<const f32x4*>(Wvol + c0 + 4);
    f32x4 ba = *reinterpret_cast<const f32x4*>(bvol + c0);
    f32x4 bb = *reinterpret_cast<const f32x4*>(bvol + c0 + 4);
    f32x4 ka = *reinterpret_cast<const f32x4*>(mk + c0);
    f32x4 kb = *reinterpret_cast<const f32x4*>(mk + c0 + 4);
    f32x4 va = *reinterpret_cast<const f32x4*>(mv + c0);
    f32x4 vb = *reinterpret_cast<const f32x4*>(mv + c0 + 4);
    f32x4 ra = *reinterpret_cast<const f32x4*>(mr + c0);
    f32x4 rb = *reinterpret_cast<const f32x4*>(mr + c0 + 4);

    float xin[8], xpr[8], wv[8], bv[8], mkv[8], mvv[8], mrv[8];
    #pragma unroll
    for (int j = 0; j < 4; j++) {
        xin[j] = xa[j]; xin[4+j] = xb[j];
        xpr[j] = pa[j]; xpr[4+j] = pb[j];
        wv[j]  = wa[j]; wv[4+j]  = wb[j];
        bv[j]  = ba[j]; bv[4+j]  = bb[j];
        mkv[j] = ka[j]; mkv[4+j] = kb[j];
        mvv[j] = va[j]; mvv[4+j] = vb[j];
        mrv[j] = ra[j]; mrv[4+j] = rb[j];
    }
    U8 ok, ov, orr;
    #pragma unroll
    for (int j = 0; j < 8; j++) {
        float g  = xin[j] * sigmoidf_(vc * wv[j] + bv[j]);
        float gp = hasp ? xpr[j] * sigmoidf_(vp * wv[j] + bv[j]) : 0.f;
        float xx = gp - g;
        ok.h[j]  = f2b(g + xx * mkv[j]);
        ov.h[j]  = f2b(g + xx * mvv[j]);
        orr.h[j] = f2b(g + xx * mrv[j]);
    }
    *reinterpret_cast<u32x4*>(xk + off) = ok.u;
    *reinterpret_cast<u32x4*>(xv + off) = ov.u;
    *reinterpret_cast<u32x4*>(xr + off) = orr.u;
}

// ---------------- K2: C = A @ W^T  (A: MxK, W: NxK, row-major bf16) ---------
#define BM_ 128
#define BN_ 128
#define BK_ 32
#define LP_ 40   // padded LDS pitch (bf16 elems): 80B rows, 16B-aligned frag reads

template<bool F32OUT>
__global__ __launch_bounds__(256) void gemm_bt(
    const u16* __restrict__ A, const u16* __restrict__ W,
    void* __restrict__ Cc, int M, int N, int K)
{
    __shared__ __align__(16) u16 Ash[BM_ * LP_];
    __shared__ __align__(16) u16 Bsh[BN_ * LP_];
    int tid  = threadIdx.x;
    int lane = tid & 63;
    int wave = tid >> 6;
    int wm = (wave >> 1) * 64;   // 2x2 wave grid over 128x128 tile
    int wn = (wave & 1) * 64;
    int r16 = lane & 15;
    int quad = lane >> 4;
    int bm = blockIdx.x, bn = blockIdx.y;

    f32x4 acc[4][4];
    #pragma unroll
    for (int mi = 0; mi < 4; mi++)
        #pragma unroll
        for (int ni = 0; ni < 4; ni++)
            acc[mi][ni] = f32x4{0.f, 0.f, 0.f, 0.f};

    const u16* Ab = A + (size_t)bm * BM_ * K;
    const u16* Wb = W + (size_t)bn * BN_ * K;

    for (int k0 = 0; k0 < K; k0 += BK_) {
        #pragma unroll
        for (int i = 0; i < 2; i++) {
            int chunk = tid + i * 256;
            int rr = chunk >> 2;
            int c8 = (chunk & 3) * 8;
            *reinterpret_cast<u32x4*>(&Ash[rr * LP_ + c8]) =
                *reinterpret_cast<const u32x4*>(Ab + (size_t)rr * K + k0 + c8);
            *reinterpret_cast<u32x4*>(&Bsh[rr * LP_ + c8]) =
                *reinterpret_cast<const u32x4*>(Wb + (size_t)rr * K + k0 + c8);
        }
        __syncthreads();
        s16x8 fa[4], fb[4];
        // A-frag: A[m=lane&15][k=quad*8+j]; B-frag (BT): same pattern on W rows
        #pragma unroll
        for (int mi = 0; mi < 4; mi++)
            fa[mi] = *reinterpret_cast<const s16x8*>(&Ash[(wm + mi * 16 + r16) * LP_ + quad * 8]);
        #pragma unroll
        for (int ni = 0; ni < 4; ni++)
            fb[ni] = *reinterpret_cast<const s16x8*>(&Bsh[(wn + ni * 16 + r16) * LP_ + quad * 8]);
        #pragma unroll
        for (int mi = 0; mi < 4; mi++)
            #pragma unroll
            for (int ni = 0; ni < 4; ni++)
                acc[mi][ni] = __builtin_amdgcn_mfma_f32_16x16x32_bf16(fa[mi], fb[ni], acc[mi][ni], 0, 0, 0);
        __syncthreads();
    }

    // D layout: col = lane&15, row = quad*4 + reg
    #pragma unroll
    for (int mi = 0; mi < 4; mi++) {
        int row0 = bm * BM_ + wm + mi * 16 + quad * 4;
        #pragma unroll
        for (int ni = 0; ni < 4; ni++) {
            int col = bn * BN_ + wn + ni * 16 + r16;
            #pragma unroll
            for (int i = 0; i < 4; i++) {
                if (F32OUT)
                    ((float*)Cc)[(size_t)(row0 + i) * N + col] = acc[mi][ni][i];
                else
                    ((u16*)Cc)[(size_t)(row0 + i) * N + col] = f2b(acc[mi][ni][i]);
            }
        }
    }
}

// ---------------- K3a: S_j = k_j^T v_j per (b,h,chunk) ----------------------
__global__ __launch_bounds__(256) void kvouter_kernel(
    const u16* __restrict__ k, const u16* __restrict__ v, float* __restrict__ S)
{
    int blk = blockIdx.x;          // bh*NC + j
    int j  = blk & (NC_ - 1);
    int bh = blk >> 3;
    int h = bh & (H_ - 1);
    int b = bh >> 4;
    __shared__ __align__(16) u16 kSh[CHUNK_ * HS_];
    __shared__ __align__(16) u16 vSh[CHUNK_ * HS_];
    int tid = threadIdx.x;
    size_t base = ((size_t)(b * T_ + j * CHUNK_)) * C_ + h * HS_;
    for (int i = tid; i < CHUNK_ * 8; i += 256) {
        int rr = i >> 3, c8 = (i & 7) * 8;
        *reinterpret_cast<u32x4*>(&kSh[rr * HS_ + c8]) =
            *reinterpret_cast<const u32x4*>(k + base + (size_t)rr * C_ + c8);
        *reinterpret_cast<u32x4*>(&vSh[rr * HS_ + c8]) =
            *reinterpret_cast<const u32x4*>(v + base + (size_t)rr * C_ + c8);
    }
    __syncthreads();
    int m  = tid >> 2;           // S row (k-channel)
    int n0 = (tid & 3) * 16;     // S col block (v-channel)
    float acc[16];
    #pragma unroll
    for (int i = 0; i < 16; i++) acc[i] = 0.f;
    for (int s = 0; s < CHUNK_; s++) {
        float km = b2f(kSh[s * HS_ + m]);
        U8 a, bb;
        a.u  = *reinterpret_cast<const u32x4*>(&vSh[s * HS_ + n0]);
        bb.u = *reinterpret_cast<const u32x4*>(&vSh[s * HS_ + n0 + 8]);
        #pragma unroll
        for (int i = 0; i < 8; i++) {
            acc[i]     += km * b2f(a.h[i]);
            acc[8 + i] += km * b2f(bb.h[i]);
        }
    }
    float* out = S + (size_t)blk * (HS_ * HS_) + m * HS_ + n0;
    #pragma unroll
    for (int i = 0; i < 16; i++) out[i] = acc[i];
}

// ---------------- K3b: states[c] = w*(state + S_c) (decay scan) -------------
__global__ __launch_bounds__(256) void scan_kernel(
    const float* __restrict__ S, const float* __restrict__ td, float* __restrict__ states)
{
    int bh = blockIdx.x;
    int h = bh & (H_ - 1);
    float w = expf(-expf(td[h]));
    int tid = threadIdx.x;
    float st[16];
    #pragma unroll
    for (int i = 0; i < 16; i++) st[i] = 0.f;
    for (int c = 0; c < NC_; c++) {
        size_t off = ((size_t)(bh * NC_ + c)) * 4096 + tid * 16;
        #pragma unroll
        for (int i = 0; i < 16; i++) st[i] = w * (st[i] + S[off + i]);
        #pragma unroll
        for (int i = 0; i < 16; i++) states[off + i] = st[i];
    }
}

// ---------------- K3c: y = r @ states[c], fused GroupNorm -------------------
// (no intra-chunk mask: y_c = w*(att@v + r@state) == r @ states[c])
__global__ __launch_bounds__(256) void rstate_gn_kernel(
    const u16* __restrict__ r, const float* __restrict__ states,
    const float* __restrict__ gnw, const float* __restrict__ gnb, u16* __restrict__ ygn)
{
    int blk = blockIdx.x;      // bh*NC + c
    int c  = blk & (NC_ - 1);
    int bh = blk >> 3;
    int h = bh & (H_ - 1);
    int b = bh >> 4;
    __shared__ __align__(16) float stSh[HS_ * HS_];
    __shared__ float gw[HS_], gb[HS_];
    int tid = threadIdx.x;
    const float* stG = states + (size_t)blk * (HS_ * HS_);
    for (int i = tid; i < (HS_ * HS_) / 4; i += 256)
        *reinterpret_cast<f32x4*>(&stSh[i * 4]) = *reinterpret_cast<const f32x4*>(stG + i * 4);
    if (tid < HS_) { gw[tid] = gnw[h * HS_ + tid]; gb[tid] = gnb[h * HS_ + tid]; }
    __syncthreads();

    size_t base = ((size_t)(b * T_ + c * CHUNK_ + tid)) * C_ + h * HS_;
    float rv[64];
    #pragma unroll
    for (int i = 0; i < 8; i++) {
        U8 u; u.u = *reinterpret_cast<const u32x4*>(r + base + i * 8);
        #pragma unroll
        for (int jj = 0; jj < 8; jj++) rv[i * 8 + jj] = b2f(u.h[jj]);
    }
    float y[64];
    #pragma unroll
    for (int i = 0; i < 64; i++) y[i] = 0.f;
    for (int m = 0; m < 64; m++) {
        float rm = rv[m];
        const float* srow = &stSh[m * 64];
        #pragma unroll
        for (int n4 = 0; n4 < 16; n4++) {
            f32x4 sv = *reinterpret_cast<const f32x4*>(srow + n4 * 4);
            y[n4 * 4 + 0] += rm * sv[0];
            y[n4 * 4 + 1] += rm * sv[1];
            y[n4 * 4 + 2] += rm * sv[2];
            y[n4 * 4 + 3] += rm * sv[3];
        }
    }
    float mu = 0.f;
    #pragma unroll
    for (int n = 0; n < 64; n++) mu += y[n];
    mu *= (1.f / 64.f);
    float var = 0.f;
    #pragma unroll
    for (int n = 0; n < 64; n++) { float d = y[n] - mu; var += d * d; }
    var *= (1.f / 64.f);
    float sc = rsqrtf(var + 1e-5f);
    #pragma unroll
    for (int i = 0; i < 8; i++) {
        U8 o;
        #pragma unroll
        for (int jj = 0; jj < 8; jj++) {
            int n = i * 8 + jj;
            o.h[jj] = f2b((y[n] - mu) * sc * gw[n] + gb[n]);
        }
        *reinterpret_cast<u32x4*>(ygn + base + i * 8) = o.u;
    }
}

// ---------------------------------------------------------------------------
extern "C" void kernel_launch(void* const* d_in, const int* in_sizes, int n_in,
                              void* d_out, int out_size, void* d_ws, size_t ws_size,
                              hipStream_t stream) {
    const float* x    = (const float*)d_in[0];
    const float* vol  = (const float*)d_in[1];
    const float* Wvol = (const float*)d_in[2];
    const float* bvol = (const float*)d_in[3];
    const float* mk   = (const float*)d_in[4];
    const float* mv   = (const float*)d_in[5];
    const float* mr   = (const float*)d_in[6];
    const float* td   = (const float*)d_in[7];
    const float* Wk   = (const float*)d_in[8];
    const float* Wv   = (const float*)d_in[9];
    const float* Wr   = (const float*)d_in[10];
    const float* Wo   = (const float*)d_in[11];
    const float* gnw  = (const float*)d_in[12];
    const float* gnb  = (const float*)d_in[13];
    float* out = (float*)d_out;

    char* ws = (char*)d_ws;
    const size_t SLOT = (size_t)B_ * T_ * C_ * 2;   // 33,554,432 B (bf16 activations)
    // slot plan (aggressive aliasing, serial stream):
    //   s0: xr  -> kb     -> ygn
    //   s1: xk  -> vb
    //   s2: xv  -> S (f32, 16.8MB) + states (f32, 16.8MB)
    //   s3: rb
    //   wtb (8MB): bf16 weights Wr,Wk,Wv,Wo
    u16* xr = (u16*)(ws + 0 * SLOT);
    u16* xk = (u16*)(ws + 1 * SLOT);
    u16* xv = (u16*)(ws + 2 * SLOT);
    u16* rb = (u16*)(ws + 3 * SLOT);
    u16* kb = (u16*)(ws + 0 * SLOT);
    u16* vb = (u16*)(ws + 1 * SLOT);
    float* S      = (float*)(ws + 2 * SLOT);
    float* states = (float*)(ws + 2 * SLOT + SLOT / 2);
    u16* ygn = (u16*)(ws + 0 * SLOT);
    u16* wrb = (u16*)(ws + 4 * SLOT);
    u16* wkb = wrb + (size_t)C_ * C_;
    u16* wvb = wkb + (size_t)C_ * C_;
    u16* wob = wvb + (size_t)C_ * C_;

    // weight conversion: 1M elems each -> 131072 threads
    int n8 = (C_ * C_) / 8;
    cvt_kernel<<<dim3(n8 / 256), dim3(256), 0, stream>>>(Wr, wrb, n8);
    cvt_kernel<<<dim3(n8 / 256), dim3(256), 0, stream>>>(Wk, wkb, n8);
    cvt_kernel<<<dim3(n8 / 256), dim3(256), 0, stream>>>(Wv, wvb, n8);
    cvt_kernel<<<dim3(n8 / 256), dim3(256), 0, stream>>>(Wo, wob, n8);

    mix_kernel<<<dim3((B_ * T_ * (C_ / 8)) / 256), dim3(256), 0, stream>>>(
        x, vol, Wvol, bvol, mk, mv, mr, xk, xv, xr);

    dim3 gg(16384 / BM_, 1024 / BN_);  // (128, 8)
    gemm_bt<false><<<gg, 256, 0, stream>>>(xr, wrb, rb, 16384, 1024, 1024);
    gemm_bt<false><<<gg, 256, 0, stream>>>(xk, wkb, kb, 16384, 1024, 1024);
    gemm_bt<false><<<gg, 256, 0, stream>>>(xv, wvb, vb, 16384, 1024, 1024);

    kvouter_kernel<<<dim3(B_ * H_ * NC_), dim3(256), 0, stream>>>(kb, vb, S);
    scan_kernel<<<dim3(B_ * H_), dim3(256), 0, stream>>>(S, td, states);
    rstate_gn_kernel<<<dim3(B_ * H_ * NC_), dim3(256), 0, stream>>>(rb, states, gnw, gnb, ygn);

    gemm_bt<true><<<gg, 256, 0, stream>>>(ygn, wob, out, 16384, 1024, 1024);
}

// Round 3
// 472.853 us; speedup vs baseline: 1.1708x; 1.1708x over previous
//
#include <hip/hip_runtime.h>

typedef unsigned short u16;
typedef __attribute__((ext_vector_type(4))) unsigned int u32x4;
typedef __attribute__((ext_vector_type(4))) float f32x4;
typedef __attribute__((ext_vector_type(8))) short s16x8;

#define B_ 8
#define T_ 2048
#define C_ 1024
#define H_ 16
#define HS_ 64
#define CHUNK_ 256
#define NC_ 8

union U8 { u32x4 u; u16 h[8]; };

__device__ __forceinline__ float b2f(u16 v) {
    union { unsigned int i; float f; } c; c.i = ((unsigned int)v) << 16; return c.f;
}
__device__ __forceinline__ u16 f2b(float f) {
    union { float f; unsigned int i; } c; c.f = f;
    unsigned int i = c.i;
    return (u16)((i + 0x7FFFu + ((i >> 16) & 1u)) >> 16);  // RNE
}
__device__ __forceinline__ float sigmoidf_(float z) { return 1.f / (1.f + expf(-z)); }

// async 16B global->LDS (lds dest = wave-uniform base + lane*16)
typedef __attribute__((address_space(1))) void GV;
typedef __attribute__((address_space(3))) void LV;
__device__ __forceinline__ void glds16(const void* g, void* l) {
    __builtin_amdgcn_global_load_lds((GV*)g, (LV*)l, 16, 0, 0);
}

// ---------------- K0: f32 -> bf16 conversion of the 4 weight matrices ------
__global__ __launch_bounds__(256) void cvt4_kernel(
    const float* __restrict__ s0, const float* __restrict__ s1,
    const float* __restrict__ s2, const float* __restrict__ s3,
    u16* __restrict__ dst)
{
    int i = blockIdx.x * 256 + threadIdx.x;   // 4 * 131072 threads, 8 elems each
    int m = i >> 17;
    const float* s = (m == 0) ? s0 : (m == 1) ? s1 : (m == 2) ? s2 : s3;
    size_t j = (size_t)(i & 131071) * 8;
    f32x4 a = *reinterpret_cast<const f32x4*>(s + j);
    f32x4 b = *reinterpret_cast<const f32x4*>(s + j + 4);
    U8 o;
    #pragma unroll
    for (int k = 0; k < 4; k++) { o.h[k] = f2b(a[k]); o.h[4 + k] = f2b(b[k]); }
    *reinterpret_cast<u32x4*>(dst + (size_t)m * C_ * C_ + j) = o.u;
}

// ---------------- K1: volatility gate + time-shift + maa mix (f32 in, bf16 out)
__global__ __launch_bounds__(256) void mix_kernel(
    const float* __restrict__ x, const float* __restrict__ vol,
    const float* __restrict__ Wvol, const float* __restrict__ bvol,
    const float* __restrict__ mk, const float* __restrict__ mv, const float* __restrict__ mr,
    u16* __restrict__ xk, u16* __restrict__ xv, u16* __restrict__ xr)
{
    int idx = blockIdx.x * 256 + threadIdx.x;      // B*T*(C/8) threads
    int c0 = (idx & (C_/8 - 1)) * 8;
    int bt = idx >> 7;
    int t  = bt & (T_ - 1);
    size_t off = (size_t)bt * C_ + c0;

    float vc = vol[bt];
    bool hasp = (t > 0);
    float vp = hasp ? vol[bt - 1] : 0.f;

    float xin[8], xpr[8], wv[8], bv[8], mkv[8], mvv[8], mrv[8];
    #pragma unroll
    for (int j = 0; j < 8; j += 4) {
        f32x4 a;
        a = *reinterpret_cast<const f32x4*>(x + off + j);
        xin[j] = a[0]; xin[j+1] = a[1]; xin[j+2] = a[2]; xin[j+3] = a[3];
        if (hasp) {
            a = *reinterpret_cast<const f32x4*>(x + off - C_ + j);
            xpr[j] = a[0]; xpr[j+1] = a[1]; xpr[j+2] = a[2]; xpr[j+3] = a[3];
        } else { xpr[j] = xpr[j+1] = xpr[j+2] = xpr[j+3] = 0.f; }
        a = *reinterpret_cast<const f32x4*>(Wvol + c0 + j);
        wv[j] = a[0]; wv[j+1] = a[1]; wv[j+2] = a[2]; wv[j+3] = a[3];
        a = *reinterpret_cast<const f32x4*>(bvol + c0 + j);
        bv[j] = a[0]; bv[j+1] = a[1]; bv[j+2] = a[2]; bv[j+3] = a[3];
        a = *reinterpret_cast<const f32x4*>(mk + c0 + j);
        mkv[j] = a[0]; mkv[j+1] = a[1]; mkv[j+2] = a[2]; mkv[j+3] = a[3];
        a = *reinterpret_cast<const f32x4*>(mv + c0 + j);
        mvv[j] = a[0]; mvv[j+1] = a[1]; mvv[j+2] = a[2]; mvv[j+3] = a[3];
        a = *reinterpret_cast<const f32x4*>(mr + c0 + j);
        mrv[j] = a[0]; mrv[j+1] = a[1]; mrv[j+2] = a[2]; mrv[j+3] = a[3];
    }
    U8 ok, ov, orr;
    #pragma unroll
    for (int j = 0; j < 8; j++) {
        float g  = xin[j] * sigmoidf_(vc * wv[j] + bv[j]);
        float gp = hasp ? xpr[j] * sigmoidf_(vp * wv[j] + bv[j]) : 0.f;
        float xx = gp - g;
        ok.h[j]  = f2b(g + xx * mkv[j]);
        ov.h[j]  = f2b(g + xx * mvv[j]);
        orr.h[j] = f2b(g + xx * mrv[j]);
    }
    *reinterpret_cast<u32x4*>(xk + off) = ok.u;
    *reinterpret_cast<u32x4*>(xv + off) = ov.u;
    *reinterpret_cast<u32x4*>(xr + off) = orr.u;
}

// ---------------- K2: C = A @ W^T  (m97 structure: global_load_lds + swizzle)
// LDS tile 128x32 bf16 unpadded; 16B chunk q=(row<<2)|ccL holds global chunk
// ccG = ccL ^ ((row>>1)&3)  -> frag ds_read_b128 is 2-way-per-phase (free)
#define BM_ 128
#define BN_ 128
#define BK_ 32

template<bool F32OUT>
__global__ __launch_bounds__(256) void gemm_bt(
    const u16* __restrict__ A, const u16* __restrict__ W,
    void* __restrict__ Cc, int M, int N, int K)
{
    __shared__ __align__(16) u16 Ash[BM_ * BK_];
    __shared__ __align__(16) u16 Bsh[BN_ * BK_];
    int tid  = threadIdx.x;
    int lane = tid & 63;
    int wave = tid >> 6;
    int wm = (wave >> 1) * 64;
    int wn = (wave & 1) * 64;
    int r16 = lane & 15;
    int quad = lane >> 4;
    int bm = blockIdx.x, bn = blockIdx.y;

    f32x4 acc[4][4];
    #pragma unroll
    for (int mi = 0; mi < 4; mi++)
        #pragma unroll
        for (int ni = 0; ni < 4; ni++)
            acc[mi][ni] = f32x4{0.f, 0.f, 0.f, 0.f};

    const u16* Ab = A + (size_t)bm * BM_ * K;
    const u16* Wb = W + (size_t)bn * BN_ * K;

    // staging: chunk q = (wave + i*4)*64 + lane, i in {0,1}
    int q0 = wave * 64 + lane, q1 = q0 + 256;
    size_t gOff0 = (size_t)(q0 >> 2) * K + ((q0 & 3) ^ ((q0 >> 3) & 3)) * 8;
    size_t gOff1 = (size_t)(q1 >> 2) * K + ((q1 & 3) ^ ((q1 >> 3) & 3)) * 8;
    u16* lA0 = &Ash[wave * 512];       // wave-uniform LDS bases
    u16* lA1 = &Ash[(wave + 4) * 512];
    u16* lB0 = &Bsh[wave * 512];
    u16* lB1 = &Bsh[(wave + 4) * 512];

    // fragment read offsets (swizzled)
    int swz = (r16 >> 1) & 3;
    int faOff[4], fbOff[4];
    #pragma unroll
    for (int i = 0; i < 4; i++) {
        faOff[i] = (wm + i * 16 + r16) * BK_ + ((quad ^ swz)) * 8;
        fbOff[i] = (wn + i * 16 + r16) * BK_ + ((quad ^ swz)) * 8;
    }

    for (int k0 = 0; k0 < K; k0 += BK_) {
        glds16(Ab + gOff0 + k0, lA0);
        glds16(Ab + gOff1 + k0, lA1);
        glds16(Wb + gOff0 + k0, lB0);
        glds16(Wb + gOff1 + k0, lB1);
        __syncthreads();
        s16x8 fa[4], fb[4];
        #pragma unroll
        for (int mi = 0; mi < 4; mi++)
            fa[mi] = *reinterpret_cast<const s16x8*>(&Ash[faOff[mi]]);
        #pragma unroll
        for (int ni = 0; ni < 4; ni++)
            fb[ni] = *reinterpret_cast<const s16x8*>(&Bsh[fbOff[ni]]);
        #pragma unroll
        for (int mi = 0; mi < 4; mi++)
            #pragma unroll
            for (int ni = 0; ni < 4; ni++)
                acc[mi][ni] = __builtin_amdgcn_mfma_f32_16x16x32_bf16(fa[mi], fb[ni], acc[mi][ni], 0, 0, 0);
        __syncthreads();
    }

    // D layout: col = lane&15, row = quad*4 + reg
    #pragma unroll
    for (int mi = 0; mi < 4; mi++) {
        int row0 = bm * BM_ + wm + mi * 16 + quad * 4;
        #pragma unroll
        for (int ni = 0; ni < 4; ni++) {
            int col = bn * BN_ + wn + ni * 16 + r16;
            #pragma unroll
            for (int i = 0; i < 4; i++) {
                if (F32OUT)
                    ((float*)Cc)[(size_t)(row0 + i) * N + col] = acc[mi][ni][i];
                else
                    ((u16*)Cc)[(size_t)(row0 + i) * N + col] = f2b(acc[mi][ni][i]);
            }
        }
    }
}

// ---------------- K3a: S_j = k_j^T v_j per (b,h,chunk) ----------------------
__global__ __launch_bounds__(256) void kvouter_kernel(
    const u16* __restrict__ k, const u16* __restrict__ v, float* __restrict__ S)
{
    int blk = blockIdx.x;          // bh*NC + j
    int j  = blk & (NC_ - 1);
    int bh = blk >> 3;
    int h = bh & (H_ - 1);
    int b = bh >> 4;
    __shared__ __align__(16) u16 kSh[CHUNK_ * HS_];
    __shared__ __align__(16) u16 vSh[CHUNK_ * HS_];
    int tid = threadIdx.x;
    size_t base = ((size_t)(b * T_ + j * CHUNK_)) * C_ + h * HS_;
    for (int i = tid; i < CHUNK_ * 8; i += 256) {
        int rr = i >> 3, c8 = (i & 7) * 8;
        *reinterpret_cast<u32x4*>(&kSh[rr * HS_ + c8]) =
            *reinterpret_cast<const u32x4*>(k + base + (size_t)rr * C_ + c8);
        *reinterpret_cast<u32x4*>(&vSh[rr * HS_ + c8]) =
            *reinterpret_cast<const u32x4*>(v + base + (size_t)rr * C_ + c8);
    }
    __syncthreads();
    int m  = tid >> 2;           // S row (k-channel)
    int n0 = (tid & 3) * 16;     // S col block (v-channel)
    float acc[16];
    #pragma unroll
    for (int i = 0; i < 16; i++) acc[i] = 0.f;
    for (int s = 0; s < CHUNK_; s++) {
        float km = b2f(kSh[s * HS_ + m]);
        U8 a, bb;
        a.u  = *reinterpret_cast<const u32x4*>(&vSh[s * HS_ + n0]);
        bb.u = *reinterpret_cast<const u32x4*>(&vSh[s * HS_ + n0 + 8]);
        #pragma unroll
        for (int i = 0; i < 8; i++) {
            acc[i]     += km * b2f(a.h[i]);
            acc[8 + i] += km * b2f(bb.h[i]);
        }
    }
    float* out = S + (size_t)blk * (HS_ * HS_) + m * HS_ + n0;
    #pragma unroll
    for (int i = 0; i < 16; i++) out[i] = acc[i];
}

// ---------------- K3b: decay scan; emits bf16 TRANSPOSED states -------------
// stT[blk][n][m] = bf16( state_use[c][m][n] )   (B-operand layout for MFMA)
__global__ __launch_bounds__(256) void scan_kernel(
    const float* __restrict__ S, const float* __restrict__ td, u16* __restrict__ stT)
{
    int bh = blockIdx.x;
    int h = bh & (H_ - 1);
    float w = expf(-expf(td[h]));
    int tid = threadIdx.x;
    int m = tid >> 2, n0 = (tid & 3) * 16;
    float st[16];
    #pragma unroll
    for (int i = 0; i < 16; i++) st[i] = 0.f;
    for (int c = 0; c < NC_; c++) {
        size_t off = ((size_t)(bh * NC_ + c)) * 4096;
        const float* sp = S + off + tid * 16;
        #pragma unroll
        for (int i = 0; i < 16; i++) st[i] = w * (st[i] + sp[i]);
        u16* op = stT + off;
        #pragma unroll
        for (int i = 0; i < 16; i++) op[(n0 + i) * HS_ + m] = f2b(st[i]);
    }
}

// ---------------- K3c: y = r @ state (MFMA), fused GroupNorm ----------------
__global__ __launch_bounds__(256) void rstate_gn_kernel(
    const u16* __restrict__ r, const u16* __restrict__ stT,
    const float* __restrict__ gnw, const float* __restrict__ gnb, u16* __restrict__ ygn)
{
    int blk = blockIdx.x;      // bh*NC + c
    int c  = blk & (NC_ - 1);
    int bh = blk >> 3;
    int h = bh & (H_ - 1);
    int b = bh >> 4;
    __shared__ __align__(16) u16 sT[HS_ * 72];   // pitch 72 u16 (144B) kills conflicts
    int tid = threadIdx.x, lane = tid & 63, wave = tid >> 6;
    int r16 = lane & 15, quad = lane >> 4;

    const u16* sg = stT + (size_t)blk * (HS_ * HS_);
    for (int i = tid; i < 512; i += 256) {       // 512 chunks of 8 u16
        int n = i >> 3, c8 = (i & 7) * 8;
        *reinterpret_cast<u32x4*>(&sT[n * 72 + c8]) =
            *reinterpret_cast<const u32x4*>(sg + n * HS_ + c8);
    }
    __syncthreads();

    size_t rowBase = (size_t)(b * T_ + c * CHUNK_ + wave * 64);
    f32x4 acc[4][4];
    #pragma unroll
    for (int mi = 0; mi < 4; mi++)
        #pragma unroll
        for (int ni = 0; ni < 4; ni++)
            acc[mi][ni] = f32x4{0.f, 0.f, 0.f, 0.f};

    #pragma unroll
    for (int ks = 0; ks < 2; ks++) {
        int kb = ks * 32 + quad * 8;
        s16x8 fa[4], fb[4];
        #pragma unroll
        for (int mi = 0; mi < 4; mi++)
            fa[mi] = *reinterpret_cast<const s16x8*>(
                r + (rowBase + mi * 16 + r16) * C_ + h * HS_ + kb);
        #pragma unroll
        for (int ni = 0; ni < 4; ni++)
            fb[ni] = *reinterpret_cast<const s16x8*>(&sT[(ni * 16 + r16) * 72 + kb]);
        #pragma unroll
        for (int mi = 0; mi < 4; mi++)
            #pragma unroll
            for (int ni = 0; ni < 4; ni++)
                acc[mi][ni] = __builtin_amdgcn_mfma_f32_16x16x32_bf16(fa[mi], fb[ni], acc[mi][ni], 0, 0, 0);
    }

    float gwv[4], gbv[4];
    #pragma unroll
    for (int ni = 0; ni < 4; ni++) {
        int col = ni * 16 + r16;
        gwv[ni] = gnw[h * HS_ + col];
        gbv[ni] = gnb[h * HS_ + col];
    }
    #pragma unroll
    for (int mi = 0; mi < 4; mi++) {
        float s1[4], s2[4];
        #pragma unroll
        for (int i = 0; i < 4; i++) {
            float s = 0.f, ss = 0.f;
            #pragma unroll
            for (int ni = 0; ni < 4; ni++) {
                float v = acc[mi][ni][i];
                s += v; ss += v * v;
            }
            s1[i] = s; s2[i] = ss;
        }
        #pragma unroll
        for (int d = 1; d < 16; d <<= 1) {
            #pragma unroll
            for (int i = 0; i < 4; i++) {
                s1[i] += __shfl_xor(s1[i], d);
                s2[i] += __shfl_xor(s2[i], d);
            }
        }
        #pragma unroll
        for (int i = 0; i < 4; i++) {
            float mu = s1[i] * (1.f / 64.f);
            float var = s2[i] * (1.f / 64.f) - mu * mu;
            float sc = rsqrtf(var + 1e-5f);
            size_t ob = (rowBase + mi * 16 + quad * 4 + i) * C_ + h * HS_;
            #pragma unroll
            for (int ni = 0; ni < 4; ni++)
                ygn[ob + ni * 16 + r16] = f2b((acc[mi][ni][i] - mu) * sc * gwv[ni] + gbv[ni]);
        }
    }
}

// ---------------------------------------------------------------------------
extern "C" void kernel_launch(void* const* d_in, const int* in_sizes, int n_in,
                              void* d_out, int out_size, void* d_ws, size_t ws_size,
                              hipStream_t stream) {
    const float* x    = (const float*)d_in[0];
    const float* vol  = (const float*)d_in[1];
    const float* Wvol = (const float*)d_in[2];
    const float* bvol = (const float*)d_in[3];
    const float* mk   = (const float*)d_in[4];
    const float* mv   = (const float*)d_in[5];
    const float* mr   = (const float*)d_in[6];
    const float* td   = (const float*)d_in[7];
    const float* Wk   = (const float*)d_in[8];
    const float* Wv   = (const float*)d_in[9];
    const float* Wr   = (const float*)d_in[10];
    const float* Wo   = (const float*)d_in[11];
    const float* gnw  = (const float*)d_in[12];
    const float* gnb  = (const float*)d_in[13];
    float* out = (float*)d_out;

    char* ws = (char*)d_ws;
    const size_t SLOT = (size_t)B_ * T_ * C_ * 2;   // 33,554,432 B
    // s0: xr -> kb -> ygn ; s1: xk -> vb ; s2: xv -> S(f32) + stT(bf16) ; s3: rb
    u16* xr = (u16*)(ws + 0 * SLOT);
    u16* xk = (u16*)(ws + 1 * SLOT);
    u16* xv = (u16*)(ws + 2 * SLOT);
    u16* rb = (u16*)(ws + 3 * SLOT);
    u16* kb = (u16*)(ws + 0 * SLOT);
    u16* vb = (u16*)(ws + 1 * SLOT);
    float* S   = (float*)(ws + 2 * SLOT);                 // 16.8 MB
    u16*   stT = (u16*)  (ws + 2 * SLOT + SLOT / 2);      // 8.4 MB
    u16* ygn = (u16*)(ws + 0 * SLOT);
    u16* wtb = (u16*)(ws + 4 * SLOT);                     // 4 bf16 weight mats
    u16* wrb = wtb;
    u16* wkb = wrb + (size_t)C_ * C_;
    u16* wvb = wkb + (size_t)C_ * C_;
    u16* wob = wvb + (size_t)C_ * C_;

    cvt4_kernel<<<dim3(4 * (C_ * C_ / 8) / 256), dim3(256), 0, stream>>>(Wr, Wk, Wv, Wo, wtb);

    mix_kernel<<<dim3((B_ * T_ * (C_ / 8)) / 256), dim3(256), 0, stream>>>(
        x, vol, Wvol, bvol, mk, mv, mr, xk, xv, xr);

    dim3 gg(16384 / BM_, 1024 / BN_);  // (128, 8)
    gemm_bt<false><<<gg, 256, 0, stream>>>(xr, wrb, rb, 16384, 1024, 1024);
    gemm_bt<false><<<gg, 256, 0, stream>>>(xk, wkb, kb, 16384, 1024, 1024);
    gemm_bt<false><<<gg, 256, 0, stream>>>(xv, wvb, vb, 16384, 1024, 1024);

    kvouter_kernel<<<dim3(B_ * H_ * NC_), dim3(256), 0, stream>>>(kb, vb, S);
    scan_kernel<<<dim3(B_ * H_), dim3(256), 0, stream>>>(S, td, stT);
    rstate_gn_kernel<<<dim3(B_ * H_ * NC_), dim3(256), 0, stream>>>(rb, stT, gnw, gnb, ygn);

    gemm_bt<true><<<gg, 256, 0, stream>>>(ygn, wob, out, 16384, 1024, 1024);
}

// Round 4
// 460.687 us; speedup vs baseline: 1.2017x; 1.0264x over previous
//
#include <hip/hip_runtime.h>

typedef unsigned short u16;
typedef __attribute__((ext_vector_type(4))) unsigned int u32x4;
typedef __attribute__((ext_vector_type(4))) float f32x4;
typedef __attribute__((ext_vector_type(8))) short s16x8;

#define B_ 8
#define T_ 2048
#define C_ 1024
#define H_ 16
#define HS_ 64
#define CHUNK_ 256
#define NC_ 8

union U8 { u32x4 u; u16 h[8]; };

__device__ __forceinline__ float b2f(u16 v) {
    union { unsigned int i; float f; } c; c.i = ((unsigned int)v) << 16; return c.f;
}
__device__ __forceinline__ u16 f2b(float f) {
    union { float f; unsigned int i; } c; c.f = f;
    unsigned int i = c.i;
    return (u16)((i + 0x7FFFu + ((i >> 16) & 1u)) >> 16);  // RNE
}
__device__ __forceinline__ float sigmoidf_(float z) { return 1.f / (1.f + expf(-z)); }

// async 16B global->LDS (lds dest = wave-uniform base + lane*16)
typedef __attribute__((address_space(1))) void GV;
typedef __attribute__((address_space(3))) void LV;
__device__ __forceinline__ void glds16(const void* g, void* l) {
    __builtin_amdgcn_global_load_lds((GV*)g, (LV*)l, 16, 0, 0);
}

// ---------------- K0: f32 -> bf16 conversion of the 4 weight matrices ------
__global__ __launch_bounds__(256) void cvt4_kernel(
    const float* __restrict__ s0, const float* __restrict__ s1,
    const float* __restrict__ s2, const float* __restrict__ s3,
    u16* __restrict__ dst)
{
    int i = blockIdx.x * 256 + threadIdx.x;   // 4 * 131072 threads, 8 elems each
    int m = i >> 17;
    const float* s = (m == 0) ? s0 : (m == 1) ? s1 : (m == 2) ? s2 : s3;
    size_t j = (size_t)(i & 131071) * 8;
    f32x4 a = *reinterpret_cast<const f32x4*>(s + j);
    f32x4 b = *reinterpret_cast<const f32x4*>(s + j + 4);
    U8 o;
    #pragma unroll
    for (int k = 0; k < 4; k++) { o.h[k] = f2b(a[k]); o.h[4 + k] = f2b(b[k]); }
    *reinterpret_cast<u32x4*>(dst + (size_t)m * C_ * C_ + j) = o.u;
}

// ---------------- K1: volatility gate + time-shift + maa mix (f32 in, bf16 out)
__global__ __launch_bounds__(256) void mix_kernel(
    const float* __restrict__ x, const float* __restrict__ vol,
    const float* __restrict__ Wvol, const float* __restrict__ bvol,
    const float* __restrict__ mk, const float* __restrict__ mv, const float* __restrict__ mr,
    u16* __restrict__ xk, u16* __restrict__ xv, u16* __restrict__ xr)
{
    int idx = blockIdx.x * 256 + threadIdx.x;      // B*T*(C/8) threads
    int c0 = (idx & (C_/8 - 1)) * 8;
    int bt = idx >> 7;
    int t  = bt & (T_ - 1);
    size_t off = (size_t)bt * C_ + c0;

    float vc = vol[bt];
    bool hasp = (t > 0);
    float vp = hasp ? vol[bt - 1] : 0.f;

    float xin[8], xpr[8], wv[8], bv[8], mkv[8], mvv[8], mrv[8];
    #pragma unroll
    for (int j = 0; j < 8; j += 4) {
        f32x4 a;
        a = *reinterpret_cast<const f32x4*>(x + off + j);
        xin[j] = a[0]; xin[j+1] = a[1]; xin[j+2] = a[2]; xin[j+3] = a[3];
        if (hasp) {
            a = *reinterpret_cast<const f32x4*>(x + off - C_ + j);
            xpr[j] = a[0]; xpr[j+1] = a[1]; xpr[j+2] = a[2]; xpr[j+3] = a[3];
        } else { xpr[j] = xpr[j+1] = xpr[j+2] = xpr[j+3] = 0.f; }
        a = *reinterpret_cast<const f32x4*>(Wvol + c0 + j);
        wv[j] = a[0]; wv[j+1] = a[1]; wv[j+2] = a[2]; wv[j+3] = a[3];
        a = *reinterpret_cast<const f32x4*>(bvol + c0 + j);
        bv[j] = a[0]; bv[j+1] = a[1]; bv[j+2] = a[2]; bv[j+3] = a[3];
        a = *reinterpret_cast<const f32x4*>(mk + c0 + j);
        mkv[j] = a[0]; mkv[j+1] = a[1]; mkv[j+2] = a[2]; mkv[j+3] = a[3];
        a = *reinterpret_cast<const f32x4*>(mv + c0 + j);
        mvv[j] = a[0]; mvv[j+1] = a[1]; mvv[j+2] = a[2]; mvv[j+3] = a[3];
        a = *reinterpret_cast<const f32x4*>(mr + c0 + j);
        mrv[j] = a[0]; mrv[j+1] = a[1]; mrv[j+2] = a[2]; mrv[j+3] = a[3];
    }
    U8 ok, ov, orr;
    #pragma unroll
    for (int j = 0; j < 8; j++) {
        float g  = xin[j] * sigmoidf_(vc * wv[j] + bv[j]);
        float gp = hasp ? xpr[j] * sigmoidf_(vp * wv[j] + bv[j]) : 0.f;
        float xx = gp - g;
        ok.h[j]  = f2b(g + xx * mkv[j]);
        ov.h[j]  = f2b(g + xx * mvv[j]);
        orr.h[j] = f2b(g + xx * mrv[j]);
    }
    *reinterpret_cast<u32x4*>(xk + off) = ok.u;
    *reinterpret_cast<u32x4*>(xv + off) = ov.u;
    *reinterpret_cast<u32x4*>(xr + off) = orr.u;
}

// ---------------- K2: C = A @ W^T  (m97 structure: global_load_lds + swizzle)
#define BM_ 128
#define BN_ 128
#define BK_ 32

template<bool F32OUT>
__global__ __launch_bounds__(256) void gemm_bt(
    const u16* __restrict__ A, const u16* __restrict__ W,
    void* __restrict__ Cc, int M, int N, int K)
{
    __shared__ __align__(16) u16 Ash[BM_ * BK_];
    __shared__ __align__(16) u16 Bsh[BN_ * BK_];
    int tid  = threadIdx.x;
    int lane = tid & 63;
    int wave = tid >> 6;
    int wm = (wave >> 1) * 64;
    int wn = (wave & 1) * 64;
    int r16 = lane & 15;
    int quad = lane >> 4;
    int bm = blockIdx.x, bn = blockIdx.y;

    f32x4 acc[4][4];
    #pragma unroll
    for (int mi = 0; mi < 4; mi++)
        #pragma unroll
        for (int ni = 0; ni < 4; ni++)
            acc[mi][ni] = f32x4{0.f, 0.f, 0.f, 0.f};

    const u16* Ab = A + (size_t)bm * BM_ * K;
    const u16* Wb = W + (size_t)bn * BN_ * K;

    // staging: chunk q = (wave + i*4)*64 + lane, i in {0,1}
    int q0 = wave * 64 + lane, q1 = q0 + 256;
    size_t gOff0 = (size_t)(q0 >> 2) * K + ((q0 & 3) ^ ((q0 >> 3) & 3)) * 8;
    size_t gOff1 = (size_t)(q1 >> 2) * K + ((q1 & 3) ^ ((q1 >> 3) & 3)) * 8;
    u16* lA0 = &Ash[wave * 512];       // wave-uniform LDS bases
    u16* lA1 = &Ash[(wave + 4) * 512];
    u16* lB0 = &Bsh[wave * 512];
    u16* lB1 = &Bsh[(wave + 4) * 512];

    // fragment read offsets (swizzled)
    int swz = (r16 >> 1) & 3;
    int faOff[4], fbOff[4];
    #pragma unroll
    for (int i = 0; i < 4; i++) {
        faOff[i] = (wm + i * 16 + r16) * BK_ + ((quad ^ swz)) * 8;
        fbOff[i] = (wn + i * 16 + r16) * BK_ + ((quad ^ swz)) * 8;
    }

    for (int k0 = 0; k0 < K; k0 += BK_) {
        glds16(Ab + gOff0 + k0, lA0);
        glds16(Ab + gOff1 + k0, lA1);
        glds16(Wb + gOff0 + k0, lB0);
        glds16(Wb + gOff1 + k0, lB1);
        __syncthreads();
        s16x8 fa[4], fb[4];
        #pragma unroll
        for (int mi = 0; mi < 4; mi++)
            fa[mi] = *reinterpret_cast<const s16x8*>(&Ash[faOff[mi]]);
        #pragma unroll
        for (int ni = 0; ni < 4; ni++)
            fb[ni] = *reinterpret_cast<const s16x8*>(&Bsh[fbOff[ni]]);
        #pragma unroll
        for (int mi = 0; mi < 4; mi++)
            #pragma unroll
            for (int ni = 0; ni < 4; ni++)
                acc[mi][ni] = __builtin_amdgcn_mfma_f32_16x16x32_bf16(fa[mi], fb[ni], acc[mi][ni], 0, 0, 0);
        __syncthreads();
    }

    // D layout: col = lane&15, row = quad*4 + reg
    #pragma unroll
    for (int mi = 0; mi < 4; mi++) {
        int row0 = bm * BM_ + wm + mi * 16 + quad * 4;
        #pragma unroll
        for (int ni = 0; ni < 4; ni++) {
            int col = bn * BN_ + wn + ni * 16 + r16;
            #pragma unroll
            for (int i = 0; i < 4; i++) {
                if (F32OUT)
                    ((float*)Cc)[(size_t)(row0 + i) * N + col] = acc[mi][ni][i];
                else
                    ((u16*)Cc)[(size_t)(row0 + i) * N + col] = f2b(acc[mi][ni][i]);
            }
        }
    }
}

// ---------------- K3a: P = v^T k per (b,h,chunk) via MFMA -------------------
// Output layout: S[blk][n][m] = sum_s v[s][n]*k[s][m]  (i.e., (kv)^T)
// LDS holds TRANSPOSED tiles kT[ch][s], vT[ch][s], pitch 136 u16
// (136/2 = 68 == 4 mod 32 -> b128 frag reads 2-way-per-phase = free)
__global__ __launch_bounds__(256) void kvouter_kernel(
    const u16* __restrict__ k, const u16* __restrict__ v, float* __restrict__ S)
{
    int blk = blockIdx.x;          // bh*NC + j
    int j  = blk & (NC_ - 1);
    int bh = blk >> 3;
    int h = bh & (H_ - 1);
    int b = bh >> 4;
    __shared__ __align__(16) u16 kT[HS_ * 136];
    __shared__ __align__(16) u16 vT[HS_ * 136];
    int tid = threadIdx.x, lane = tid & 63, wave = tid >> 6;
    int r16 = lane & 15, quad = lane >> 4;
    int n0 = (wave >> 1) * 32, m0 = (wave & 1) * 32;
    int a = tid & 7, c8 = a * 8;

    f32x4 acc[2][2];
    #pragma unroll
    for (int ni = 0; ni < 2; ni++)
        #pragma unroll
        for (int mi = 0; mi < 2; mi++)
            acc[ni][mi] = f32x4{0.f, 0.f, 0.f, 0.f};

    size_t base = ((size_t)(b * T_ + j * CHUNK_)) * C_ + h * HS_;
    #pragma unroll
    for (int half = 0; half < 2; half++) {
        size_t hb = base + (size_t)half * 128 * C_;
        // stage + transpose: 4 chunks of 16B per tensor per thread,
        // scatter-write with jj^a swizzle (conflict-free banks)
        #pragma unroll
        for (int i = 0; i < 4; i++) {
            int s = (tid + i * 256) >> 3;
            U8 uk, uv;
            uk.u = *reinterpret_cast<const u32x4*>(k + hb + (size_t)s * C_ + c8);
            uv.u = *reinterpret_cast<const u32x4*>(v + hb + (size_t)s * C_ + c8);
            #pragma unroll
            for (int jj = 0; jj < 8; jj++) {
                int w = jj ^ a;
                kT[(c8 + w) * 136 + s] = uk.h[w];
                vT[(c8 + w) * 136 + s] = uv.h[w];
            }
        }
        __syncthreads();
        #pragma unroll
        for (int ks = 0; ks < 4; ks++) {
            s16x8 fa[2], fb[2];
            #pragma unroll
            for (int ni = 0; ni < 2; ni++)
                fa[ni] = *reinterpret_cast<const s16x8*>(
                    &vT[(n0 + ni * 16 + r16) * 136 + ks * 32 + quad * 8]);
            #pragma unroll
            for (int mi = 0; mi < 2; mi++)
                fb[mi] = *reinterpret_cast<const s16x8*>(
                    &kT[(m0 + mi * 16 + r16) * 136 + ks * 32 + quad * 8]);
            #pragma unroll
            for (int ni = 0; ni < 2; ni++)
                #pragma unroll
                for (int mi = 0; mi < 2; mi++)
                    acc[ni][mi] = __builtin_amdgcn_mfma_f32_16x16x32_bf16(fa[ni], fb[mi], acc[ni][mi], 0, 0, 0);
        }
        __syncthreads();
    }
    // D layout: col(lane&15) = m, row(quad*4+reg) = n
    float* out = S + (size_t)blk * (HS_ * HS_);
    #pragma unroll
    for (int ni = 0; ni < 2; ni++)
        #pragma unroll
        for (int mi = 0; mi < 2; mi++)
            #pragma unroll
            for (int i = 0; i < 4; i++)
                out[(n0 + ni * 16 + quad * 4 + i) * HS_ + m0 + mi * 16 + r16] = acc[ni][mi][i];
}

// ---------------- K3b: decay scan (elementwise in (n,m) layout) -------------
// stT[blk][n][m] = bf16 running w*(st + P_c)  -> exactly rstate's B-operand
__global__ __launch_bounds__(256) void scan_kernel(
    const float* __restrict__ S, const float* __restrict__ td, u16* __restrict__ stT)
{
    int bh = blockIdx.x;
    int h = bh & (H_ - 1);
    float w = expf(-expf(td[h]));
    int tid = threadIdx.x;
    float st[16];
    #pragma unroll
    for (int i = 0; i < 16; i++) st[i] = 0.f;
    for (int c = 0; c < NC_; c++) {
        size_t off = ((size_t)(bh * NC_ + c)) * 4096 + tid * 16;
        const float* sp = S + off;
        #pragma unroll
        for (int i = 0; i < 16; i++) st[i] = w * (st[i] + sp[i]);
        U8 o0, o1;
        #pragma unroll
        for (int i = 0; i < 8; i++) { o0.h[i] = f2b(st[i]); o1.h[i] = f2b(st[8 + i]); }
        *reinterpret_cast<u32x4*>(stT + off)     = o0.u;
        *reinterpret_cast<u32x4*>(stT + off + 8) = o1.u;
    }
}

// ---------------- K3c: y = r @ state (MFMA), fused GroupNorm ----------------
__global__ __launch_bounds__(256) void rstate_gn_kernel(
    const u16* __restrict__ r, const u16* __restrict__ stT,
    const float* __restrict__ gnw, const float* __restrict__ gnb, u16* __restrict__ ygn)
{
    int blk = blockIdx.x;      // bh*NC + c
    int c  = blk & (NC_ - 1);
    int bh = blk >> 3;
    int h = bh & (H_ - 1);
    int b = bh >> 4;
    __shared__ __align__(16) u16 sT[HS_ * 72];   // pitch 72 u16
    int tid = threadIdx.x, lane = tid & 63, wave = tid >> 6;
    int r16 = lane & 15, quad = lane >> 4;

    const u16* sg = stT + (size_t)blk * (HS_ * HS_);
    for (int i = tid; i < 512; i += 256) {       // 512 chunks of 8 u16
        int n = i >> 3, c8 = (i & 7) * 8;
        *reinterpret_cast<u32x4*>(&sT[n * 72 + c8]) =
            *reinterpret_cast<const u32x4*>(sg + n * HS_ + c8);
    }
    __syncthreads();

    size_t rowBase = (size_t)(b * T_ + c * CHUNK_ + wave * 64);
    f32x4 acc[4][4];
    #pragma unroll
    for (int mi = 0; mi < 4; mi++)
        #pragma unroll
        for (int ni = 0; ni < 4; ni++)
            acc[mi][ni] = f32x4{0.f, 0.f, 0.f, 0.f};

    #pragma unroll
    for (int ks = 0; ks < 2; ks++) {
        int kb = ks * 32 + quad * 8;
        s16x8 fa[4], fb[4];
        #pragma unroll
        for (int mi = 0; mi < 4; mi++)
            fa[mi] = *reinterpret_cast<const s16x8*>(
                r + (rowBase + mi * 16 + r16) * C_ + h * HS_ + kb);
        #pragma unroll
        for (int ni = 0; ni < 4; ni++)
            fb[ni] = *reinterpret_cast<const s16x8*>(&sT[(ni * 16 + r16) * 72 + kb]);
        #pragma unroll
        for (int mi = 0; mi < 4; mi++)
            #pragma unroll
            for (int ni = 0; ni < 4; ni++)
                acc[mi][ni] = __builtin_amdgcn_mfma_f32_16x16x32_bf16(fa[mi], fb[ni], acc[mi][ni], 0, 0, 0);
    }

    float gwv[4], gbv[4];
    #pragma unroll
    for (int ni = 0; ni < 4; ni++) {
        int col = ni * 16 + r16;
        gwv[ni] = gnw[h * HS_ + col];
        gbv[ni] = gnb[h * HS_ + col];
    }
    #pragma unroll
    for (int mi = 0; mi < 4; mi++) {
        float s1[4], s2[4];
        #pragma unroll
        for (int i = 0; i < 4; i++) {
            float s = 0.f, ss = 0.f;
            #pragma unroll
            for (int ni = 0; ni < 4; ni++) {
                float v = acc[mi][ni][i];
                s += v; ss += v * v;
            }
            s1[i] = s; s2[i] = ss;
        }
        #pragma unroll
        for (int d = 1; d < 16; d <<= 1) {
            #pragma unroll
            for (int i = 0; i < 4; i++) {
                s1[i] += __shfl_xor(s1[i], d);
                s2[i] += __shfl_xor(s2[i], d);
            }
        }
        #pragma unroll
        for (int i = 0; i < 4; i++) {
            float mu = s1[i] * (1.f / 64.f);
            float var = s2[i] * (1.f / 64.f) - mu * mu;
            float sc = rsqrtf(var + 1e-5f);
            size_t ob = (rowBase + mi * 16 + quad * 4 + i) * C_ + h * HS_;
            #pragma unroll
            for (int ni = 0; ni < 4; ni++)
                ygn[ob + ni * 16 + r16] = f2b((acc[mi][ni][i] - mu) * sc * gwv[ni] + gbv[ni]);
        }
    }
}

// ---------------------------------------------------------------------------
extern "C" void kernel_launch(void* const* d_in, const int* in_sizes, int n_in,
                              void* d_out, int out_size, void* d_ws, size_t ws_size,
                              hipStream_t stream) {
    const float* x    = (const float*)d_in[0];
    const float* vol  = (const float*)d_in[1];
    const float* Wvol = (const float*)d_in[2];
    const float* bvol = (const float*)d_in[3];
    const float* mk   = (const float*)d_in[4];
    const float* mv   = (const float*)d_in[5];
    const float* mr   = (const float*)d_in[6];
    const float* td   = (const float*)d_in[7];
    const float* Wk   = (const float*)d_in[8];
    const float* Wv   = (const float*)d_in[9];
    const float* Wr   = (const float*)d_in[10];
    const float* Wo   = (const float*)d_in[11];
    const float* gnw  = (const float*)d_in[12];
    const float* gnb  = (const float*)d_in[13];
    float* out = (float*)d_out;

    char* ws = (char*)d_ws;
    const size_t SLOT = (size_t)B_ * T_ * C_ * 2;   // 33,554,432 B
    // s0: xr -> kb -> ygn ; s1: xk -> vb ; s2: xv -> S(f32) + stT(bf16) ; s3: rb
    u16* xr = (u16*)(ws + 0 * SLOT);
    u16* xk = (u16*)(ws + 1 * SLOT);
    u16* xv = (u16*)(ws + 2 * SLOT);
    u16* rb = (u16*)(ws + 3 * SLOT);
    u16* kb = (u16*)(ws + 0 * SLOT);
    u16* vb = (u16*)(ws + 1 * SLOT);
    float* S   = (float*)(ws + 2 * SLOT);                 // 16.8 MB
    u16*   stT = (u16*)  (ws + 2 * SLOT + SLOT / 2);      // 8.4 MB
    u16* ygn = (u16*)(ws + 0 * SLOT);
    u16* wtb = (u16*)(ws + 4 * SLOT);                     // 4 bf16 weight mats
    u16* wrb = wtb;
    u16* wkb = wrb + (size_t)C_ * C_;
    u16* wvb = wkb + (size_t)C_ * C_;
    u16* wob = wvb + (size_t)C_ * C_;

    cvt4_kernel<<<dim3(4 * (C_ * C_ / 8) / 256), dim3(256), 0, stream>>>(Wr, Wk, Wv, Wo, wtb);

    mix_kernel<<<dim3((B_ * T_ * (C_ / 8)) / 256), dim3(256), 0, stream>>>(
        x, vol, Wvol, bvol, mk, mv, mr, xk, xv, xr);

    dim3 gg(16384 / BM_, 1024 / BN_);  // (128, 8)
    gemm_bt<false><<<gg, 256, 0, stream>>>(xr, wrb, rb, 16384, 1024, 1024);
    gemm_bt<false><<<gg, 256, 0, stream>>>(xk, wkb, kb, 16384, 1024, 1024);
    gemm_bt<false><<<gg, 256, 0, stream>>>(xv, wvb, vb, 16384, 1024, 1024);

    kvouter_kernel<<<dim3(B_ * H_ * NC_), dim3(256), 0, stream>>>(kb, vb, S);
    scan_kernel<<<dim3(B_ * H_), dim3(256), 0, stream>>>(S, td, stT);
    rstate_gn_kernel<<<dim3(B_ * H_ * NC_), dim3(256), 0, stream>>>(rb, stT, gnw, gnb, ygn);

    gemm_bt<true><<<gg, 256, 0, stream>>>(ygn, wob, out, 16384, 1024, 1024);
}

// Round 5
// 415.261 us; speedup vs baseline: 1.3332x; 1.1094x over previous
//
#include <hip/hip_runtime.h>

typedef unsigned short u16;
typedef __attribute__((ext_vector_type(4))) unsigned int u32x4;
typedef __attribute__((ext_vector_type(4))) float f32x4;
typedef __attribute__((ext_vector_type(8))) short s16x8;

#define B_ 8
#define T_ 2048
#define C_ 1024
#define H_ 16
#define HS_ 64
#define CHUNK_ 256
#define NC_ 8

union U8 { u32x4 u; u16 h[8]; };

__device__ __forceinline__ float b2f(u16 v) {
    union { unsigned int i; float f; } c; c.i = ((unsigned int)v) << 16; return c.f;
}
__device__ __forceinline__ u16 f2b(float f) {
    union { float f; unsigned int i; } c; c.f = f;
    unsigned int i = c.i;
    return (u16)((i + 0x7FFFu + ((i >> 16) & 1u)) >> 16);  // RNE
}
__device__ __forceinline__ float sigmoidf_(float z) { return 1.f / (1.f + expf(-z)); }

// async 16B global->LDS (lds dest = wave-uniform base + lane*16)
typedef __attribute__((address_space(1))) void GV;
typedef __attribute__((address_space(3))) void LV;
__device__ __forceinline__ void glds16(const void* g, void* l) {
    __builtin_amdgcn_global_load_lds((GV*)g, (LV*)l, 16, 0, 0);
}

// ---------------- K0: f32 -> bf16 conversion of the 4 weight matrices ------
__global__ __launch_bounds__(256) void cvt4_kernel(
    const float* __restrict__ s0, const float* __restrict__ s1,
    const float* __restrict__ s2, const float* __restrict__ s3,
    u16* __restrict__ dst)
{
    int i = blockIdx.x * 256 + threadIdx.x;   // 4 * 131072 threads, 8 elems each
    int m = i >> 17;
    const float* s = (m == 0) ? s0 : (m == 1) ? s1 : (m == 2) ? s2 : s3;
    size_t j = (size_t)(i & 131071) * 8;
    f32x4 a = *reinterpret_cast<const f32x4*>(s + j);
    f32x4 b = *reinterpret_cast<const f32x4*>(s + j + 4);
    U8 o;
    #pragma unroll
    for (int k = 0; k < 4; k++) { o.h[k] = f2b(a[k]); o.h[4 + k] = f2b(b[k]); }
    *reinterpret_cast<u32x4*>(dst + (size_t)m * C_ * C_ + j) = o.u;
}

// ---------------- K1: volatility gate + time-shift + maa mix (f32 in, bf16 out)
__global__ __launch_bounds__(256) void mix_kernel(
    const float* __restrict__ x, const float* __restrict__ vol,
    const float* __restrict__ Wvol, const float* __restrict__ bvol,
    const float* __restrict__ mk, const float* __restrict__ mv, const float* __restrict__ mr,
    u16* __restrict__ xk, u16* __restrict__ xv, u16* __restrict__ xr)
{
    int idx = blockIdx.x * 256 + threadIdx.x;      // B*T*(C/8) threads
    int c0 = (idx & (C_/8 - 1)) * 8;
    int bt = idx >> 7;
    int t  = bt & (T_ - 1);
    size_t off = (size_t)bt * C_ + c0;

    float vc = vol[bt];
    bool hasp = (t > 0);
    float vp = hasp ? vol[bt - 1] : 0.f;

    float xin[8], xpr[8], wv[8], bv[8], mkv[8], mvv[8], mrv[8];
    #pragma unroll
    for (int j = 0; j < 8; j += 4) {
        f32x4 a;
        a = *reinterpret_cast<const f32x4*>(x + off + j);
        xin[j] = a[0]; xin[j+1] = a[1]; xin[j+2] = a[2]; xin[j+3] = a[3];
        if (hasp) {
            a = *reinterpret_cast<const f32x4*>(x + off - C_ + j);
            xpr[j] = a[0]; xpr[j+1] = a[1]; xpr[j+2] = a[2]; xpr[j+3] = a[3];
        } else { xpr[j] = xpr[j+1] = xpr[j+2] = xpr[j+3] = 0.f; }
        a = *reinterpret_cast<const f32x4*>(Wvol + c0 + j);
        wv[j] = a[0]; wv[j+1] = a[1]; wv[j+2] = a[2]; wv[j+3] = a[3];
        a = *reinterpret_cast<const f32x4*>(bvol + c0 + j);
        bv[j] = a[0]; bv[j+1] = a[1]; bv[j+2] = a[2]; bv[j+3] = a[3];
        a = *reinterpret_cast<const f32x4*>(mk + c0 + j);
        mkv[j] = a[0]; mkv[j+1] = a[1]; mkv[j+2] = a[2]; mkv[j+3] = a[3];
        a = *reinterpret_cast<const f32x4*>(mv + c0 + j);
        mvv[j] = a[0]; mvv[j+1] = a[1]; mvv[j+2] = a[2]; mvv[j+3] = a[3];
        a = *reinterpret_cast<const f32x4*>(mr + c0 + j);
        mrv[j] = a[0]; mrv[j+1] = a[1]; mrv[j+2] = a[2]; mrv[j+3] = a[3];
    }
    U8 ok, ov, orr;
    #pragma unroll
    for (int j = 0; j < 8; j++) {
        float g  = xin[j] * sigmoidf_(vc * wv[j] + bv[j]);
        float gp = hasp ? xpr[j] * sigmoidf_(vp * wv[j] + bv[j]) : 0.f;
        float xx = gp - g;
        ok.h[j]  = f2b(g + xx * mkv[j]);
        ov.h[j]  = f2b(g + xx * mvv[j]);
        orr.h[j] = f2b(g + xx * mrv[j]);
    }
    *reinterpret_cast<u32x4*>(xk + off) = ok.u;
    *reinterpret_cast<u32x4*>(xv + off) = ov.u;
    *reinterpret_cast<u32x4*>(xr + off) = orr.u;
}

// ---------------- K2: C = A @ W^T  (BK=64: half the barrier drains) ---------
// LDS tile 128x64 u16 (128B rows). Store swizzle: 16B chunk at (row, ccL)
// holds global chunk ccG = ccL ^ (row & 7). Global side stays coalesced
// (each 8-lane group covers one full 128B row segment). Frag reads apply the
// same XOR -> per-quad rows spread over all 8 4-bank groups, 2-way = free.
#define BM_ 128
#define BN_ 128
#define BK_ 64

template<bool F32OUT>
__global__ __launch_bounds__(256) void gemm_bt(
    const u16* __restrict__ A, const u16* __restrict__ W,
    void* __restrict__ Cc, int M, int N, int K)
{
    __shared__ __align__(16) u16 Ash[BM_ * BK_];
    __shared__ __align__(16) u16 Bsh[BN_ * BK_];
    int tid  = threadIdx.x;
    int lane = tid & 63;
    int wave = tid >> 6;
    int wm = (wave >> 1) * 64;
    int wn = (wave & 1) * 64;
    int r16 = lane & 15;
    int quad = lane >> 4;
    int bm = blockIdx.x, bn = blockIdx.y;

    f32x4 acc[4][4];
    #pragma unroll
    for (int mi = 0; mi < 4; mi++)
        #pragma unroll
        for (int ni = 0; ni < 4; ni++)
            acc[mi][ni] = f32x4{0.f, 0.f, 0.f, 0.f};

    const u16* Ab = A + (size_t)bm * BM_ * K;
    const u16* Wb = W + (size_t)bn * BN_ * K;

    // staging: position p = (i*4+wave)*64 + lane, i in 0..3 (1024 chunks of 16B)
    size_t gOf[4];
    u16 *ldA[4], *ldB[4];
    #pragma unroll
    for (int i = 0; i < 4; i++) {
        int p = (i * 4 + wave) * 64 + lane;
        int row = p >> 3;
        int ccG = (p & 7) ^ (row & 7);
        gOf[i] = (size_t)row * K + ccG * 8;
        ldA[i] = &Ash[(i * 4 + wave) * 512];   // wave-uniform base (512 u16 = 1KB)
        ldB[i] = &Bsh[(i * 4 + wave) * 512];
    }

    // fragment LDS element offsets (swizzled), ks in {0,1} covers k=0..63
    int faOff[2][4], fbOff[2][4];
    #pragma unroll
    for (int ks = 0; ks < 2; ks++) {
        #pragma unroll
        for (int i = 0; i < 4; i++) {
            int rowA = wm + i * 16 + r16;
            faOff[ks][i] = rowA * BK_ + (((ks * 4 + quad) ^ (rowA & 7)) * 8);
            int rowB = wn + i * 16 + r16;
            fbOff[ks][i] = rowB * BK_ + (((ks * 4 + quad) ^ (rowB & 7)) * 8);
        }
    }

    for (int k0 = 0; k0 < K; k0 += BK_) {
        #pragma unroll
        for (int i = 0; i < 4; i++) {
            glds16(Ab + gOf[i] + k0, ldA[i]);
            glds16(Wb + gOf[i] + k0, ldB[i]);
        }
        __syncthreads();
        #pragma unroll
        for (int ks = 0; ks < 2; ks++) {
            s16x8 fa[4], fb[4];
            #pragma unroll
            for (int mi = 0; mi < 4; mi++)
                fa[mi] = *reinterpret_cast<const s16x8*>(&Ash[faOff[ks][mi]]);
            #pragma unroll
            for (int ni = 0; ni < 4; ni++)
                fb[ni] = *reinterpret_cast<const s16x8*>(&Bsh[fbOff[ks][ni]]);
            #pragma unroll
            for (int mi = 0; mi < 4; mi++)
                #pragma unroll
                for (int ni = 0; ni < 4; ni++)
                    acc[mi][ni] = __builtin_amdgcn_mfma_f32_16x16x32_bf16(fa[mi], fb[ni], acc[mi][ni], 0, 0, 0);
        }
        __syncthreads();
    }

    // D layout: col = lane&15, row = quad*4 + reg
    #pragma unroll
    for (int mi = 0; mi < 4; mi++) {
        int row0 = bm * BM_ + wm + mi * 16 + quad * 4;
        #pragma unroll
        for (int ni = 0; ni < 4; ni++) {
            int col = bn * BN_ + wn + ni * 16 + r16;
            #pragma unroll
            for (int i = 0; i < 4; i++) {
                if (F32OUT)
                    ((float*)Cc)[(size_t)(row0 + i) * N + col] = acc[mi][ni][i];
                else
                    ((u16*)Cc)[(size_t)(row0 + i) * N + col] = f2b(acc[mi][ni][i]);
            }
        }
    }
}

// ---------------- K3a: P = v^T k per (b,h,chunk) via MFMA -------------------
// Output layout: S[blk][n][m] = sum_s v[s][n]*k[s][m]  (i.e., (kv)^T)
__global__ __launch_bounds__(256) void kvouter_kernel(
    const u16* __restrict__ k, const u16* __restrict__ v, float* __restrict__ S)
{
    int blk = blockIdx.x;          // bh*NC + j
    int j  = blk & (NC_ - 1);
    int bh = blk >> 3;
    int h = bh & (H_ - 1);
    int b = bh >> 4;
    __shared__ __align__(16) u16 kT[HS_ * 136];
    __shared__ __align__(16) u16 vT[HS_ * 136];
    int tid = threadIdx.x, lane = tid & 63, wave = tid >> 6;
    int r16 = lane & 15, quad = lane >> 4;
    int n0 = (wave >> 1) * 32, m0 = (wave & 1) * 32;
    int a = tid & 7, c8 = a * 8;

    f32x4 acc[2][2];
    #pragma unroll
    for (int ni = 0; ni < 2; ni++)
        #pragma unroll
        for (int mi = 0; mi < 2; mi++)
            acc[ni][mi] = f32x4{0.f, 0.f, 0.f, 0.f};

    size_t base = ((size_t)(b * T_ + j * CHUNK_)) * C_ + h * HS_;
    #pragma unroll
    for (int half = 0; half < 2; half++) {
        size_t hb = base + (size_t)half * 128 * C_;
        #pragma unroll
        for (int i = 0; i < 4; i++) {
            int s = (tid + i * 256) >> 3;
            U8 uk, uv;
            uk.u = *reinterpret_cast<const u32x4*>(k + hb + (size_t)s * C_ + c8);
            uv.u = *reinterpret_cast<const u32x4*>(v + hb + (size_t)s * C_ + c8);
            #pragma unroll
            for (int jj = 0; jj < 8; jj++) {
                int w = jj ^ a;
                kT[(c8 + w) * 136 + s] = uk.h[w];
                vT[(c8 + w) * 136 + s] = uv.h[w];
            }
        }
        __syncthreads();
        #pragma unroll
        for (int ks = 0; ks < 4; ks++) {
            s16x8 fa[2], fb[2];
            #pragma unroll
            for (int ni = 0; ni < 2; ni++)
                fa[ni] = *reinterpret_cast<const s16x8*>(
                    &vT[(n0 + ni * 16 + r16) * 136 + ks * 32 + quad * 8]);
            #pragma unroll
            for (int mi = 0; mi < 2; mi++)
                fb[mi] = *reinterpret_cast<const s16x8*>(
                    &kT[(m0 + mi * 16 + r16) * 136 + ks * 32 + quad * 8]);
            #pragma unroll
            for (int ni = 0; ni < 2; ni++)
                #pragma unroll
                for (int mi = 0; mi < 2; mi++)
                    acc[ni][mi] = __builtin_amdgcn_mfma_f32_16x16x32_bf16(fa[ni], fb[mi], acc[ni][mi], 0, 0, 0);
        }
        __syncthreads();
    }
    // D layout: col(lane&15) = m, row(quad*4+reg) = n
    float* out = S + (size_t)blk * (HS_ * HS_);
    #pragma unroll
    for (int ni = 0; ni < 2; ni++)
        #pragma unroll
        for (int mi = 0; mi < 2; mi++)
            #pragma unroll
            for (int i = 0; i < 4; i++)
                out[(n0 + ni * 16 + quad * 4 + i) * HS_ + m0 + mi * 16 + r16] = acc[ni][mi][i];
}

// ---------------- K3b: decay scan (elementwise in (n,m) layout) -------------
__global__ __launch_bounds__(256) void scan_kernel(
    const float* __restrict__ S, const float* __restrict__ td, u16* __restrict__ stT)
{
    int bh = blockIdx.x;
    int h = bh & (H_ - 1);
    float w = expf(-expf(td[h]));
    int tid = threadIdx.x;
    float st[16];
    #pragma unroll
    for (int i = 0; i < 16; i++) st[i] = 0.f;
    for (int c = 0; c < NC_; c++) {
        size_t off = ((size_t)(bh * NC_ + c)) * 4096 + tid * 16;
        const float* sp = S + off;
        #pragma unroll
        for (int i = 0; i < 16; i++) st[i] = w * (st[i] + sp[i]);
        U8 o0, o1;
        #pragma unroll
        for (int i = 0; i < 8; i++) { o0.h[i] = f2b(st[i]); o1.h[i] = f2b(st[8 + i]); }
        *reinterpret_cast<u32x4*>(stT + off)     = o0.u;
        *reinterpret_cast<u32x4*>(stT + off + 8) = o1.u;
    }
}

// ---------------- K3c: y = r @ state (MFMA), fused GroupNorm ----------------
__global__ __launch_bounds__(256) void rstate_gn_kernel(
    const u16* __restrict__ r, const u16* __restrict__ stT,
    const float* __restrict__ gnw, const float* __restrict__ gnb, u16* __restrict__ ygn)
{
    int blk = blockIdx.x;      // bh*NC + c
    int c  = blk & (NC_ - 1);
    int bh = blk >> 3;
    int h = bh & (H_ - 1);
    int b = bh >> 4;
    __shared__ __align__(16) u16 sT[HS_ * 72];   // pitch 72 u16
    int tid = threadIdx.x, lane = tid & 63, wave = tid >> 6;
    int r16 = lane & 15, quad = lane >> 4;

    const u16* sg = stT + (size_t)blk * (HS_ * HS_);
    for (int i = tid; i < 512; i += 256) {       // 512 chunks of 8 u16
        int n = i >> 3, c8 = (i & 7) * 8;
        *reinterpret_cast<u32x4*>(&sT[n * 72 + c8]) =
            *reinterpret_cast<const u32x4*>(sg + n * HS_ + c8);
    }
    __syncthreads();

    size_t rowBase = (size_t)(b * T_ + c * CHUNK_ + wave * 64);
    f32x4 acc[4][4];
    #pragma unroll
    for (int mi = 0; mi < 4; mi++)
        #pragma unroll
        for (int ni = 0; ni < 4; ni++)
            acc[mi][ni] = f32x4{0.f, 0.f, 0.f, 0.f};

    #pragma unroll
    for (int ks = 0; ks < 2; ks++) {
        int kb = ks * 32 + quad * 8;
        s16x8 fa[4], fb[4];
        #pragma unroll
        for (int mi = 0; mi < 4; mi++)
            fa[mi] = *reinterpret_cast<const s16x8*>(
                r + (rowBase + mi * 16 + r16) * C_ + h * HS_ + kb);
        #pragma unroll
        for (int ni = 0; ni < 4; ni++)
            fb[ni] = *reinterpret_cast<const s16x8*>(&sT[(ni * 16 + r16) * 72 + kb]);
        #pragma unroll
        for (int mi = 0; mi < 4; mi++)
            #pragma unroll
            for (int ni = 0; ni < 4; ni++)
                acc[mi][ni] = __builtin_amdgcn_mfma_f32_16x16x32_bf16(fa[mi], fb[ni], acc[mi][ni], 0, 0, 0);
    }

    float gwv[4], gbv[4];
    #pragma unroll
    for (int ni = 0; ni < 4; ni++) {
        int col = ni * 16 + r16;
        gwv[ni] = gnw[h * HS_ + col];
        gbv[ni] = gnb[h * HS_ + col];
    }
    #pragma unroll
    for (int mi = 0; mi < 4; mi++) {
        float s1[4], s2[4];
        #pragma unroll
        for (int i = 0; i < 4; i++) {
            float s = 0.f, ss = 0.f;
            #pragma unroll
            for (int ni = 0; ni < 4; ni++) {
                float v = acc[mi][ni][i];
                s += v; ss += v * v;
            }
            s1[i] = s; s2[i] = ss;
        }
        #pragma unroll
        for (int d = 1; d < 16; d <<= 1) {
            #pragma unroll
            for (int i = 0; i < 4; i++) {
                s1[i] += __shfl_xor(s1[i], d);
                s2[i] += __shfl_xor(s2[i], d);
            }
        }
        #pragma unroll
        for (int i = 0; i < 4; i++) {
            float mu = s1[i] * (1.f / 64.f);
            float var = s2[i] * (1.f / 64.f) - mu * mu;
            float sc = rsqrtf(var + 1e-5f);
            size_t ob = (rowBase + mi * 16 + quad * 4 + i) * C_ + h * HS_;
            #pragma unroll
            for (int ni = 0; ni < 4; ni++)
                ygn[ob + ni * 16 + r16] = f2b((acc[mi][ni][i] - mu) * sc * gwv[ni] + gbv[ni]);
        }
    }
}

// ---------------------------------------------------------------------------
extern "C" void kernel_launch(void* const* d_in, const int* in_sizes, int n_in,
                              void* d_out, int out_size, void* d_ws, size_t ws_size,
                              hipStream_t stream) {
    const float* x    = (const float*)d_in[0];
    const float* vol  = (const float*)d_in[1];
    const float* Wvol = (const float*)d_in[2];
    const float* bvol = (const float*)d_in[3];
    const float* mk   = (const float*)d_in[4];
    const float* mv   = (const float*)d_in[5];
    const float* mr   = (const float*)d_in[6];
    const float* td   = (const float*)d_in[7];
    const float* Wk   = (const float*)d_in[8];
    const float* Wv   = (const float*)d_in[9];
    const float* Wr   = (const float*)d_in[10];
    const float* Wo   = (const float*)d_in[11];
    const float* gnw  = (const float*)d_in[12];
    const float* gnb  = (const float*)d_in[13];
    float* out = (float*)d_out;

    char* ws = (char*)d_ws;
    const size_t SLOT = (size_t)B_ * T_ * C_ * 2;   // 33,554,432 B
    // s0: xr -> kb -> ygn ; s1: xk -> vb ; s2: xv -> S(f32) + stT(bf16) ; s3: rb
    u16* xr = (u16*)(ws + 0 * SLOT);
    u16* xk = (u16*)(ws + 1 * SLOT);
    u16* xv = (u16*)(ws + 2 * SLOT);
    u16* rb = (u16*)(ws + 3 * SLOT);
    u16* kb = (u16*)(ws + 0 * SLOT);
    u16* vb = (u16*)(ws + 1 * SLOT);
    float* S   = (float*)(ws + 2 * SLOT);                 // 16.8 MB
    u16*   stT = (u16*)  (ws + 2 * SLOT + SLOT / 2);      // 8.4 MB
    u16* ygn = (u16*)(ws + 0 * SLOT);
    u16* wtb = (u16*)(ws + 4 * SLOT);                     // 4 bf16 weight mats
    u16* wrb = wtb;
    u16* wkb = wrb + (size_t)C_ * C_;
    u16* wvb = wkb + (size_t)C_ * C_;
    u16* wob = wvb + (size_t)C_ * C_;

    cvt4_kernel<<<dim3(4 * (C_ * C_ / 8) / 256), dim3(256), 0, stream>>>(Wr, Wk, Wv, Wo, wtb);

    mix_kernel<<<dim3((B_ * T_ * (C_ / 8)) / 256), dim3(256), 0, stream>>>(
        x, vol, Wvol, bvol, mk, mv, mr, xk, xv, xr);

    dim3 gg(16384 / BM_, 1024 / BN_);  // (128, 8)
    gemm_bt<false><<<gg, 256, 0, stream>>>(xr, wrb, rb, 16384, 1024, 1024);
    gemm_bt<false><<<gg, 256, 0, stream>>>(xk, wkb, kb, 16384, 1024, 1024);
    gemm_bt<false><<<gg, 256, 0, stream>>>(xv, wvb, vb, 16384, 1024, 1024);

    kvouter_kernel<<<dim3(B_ * H_ * NC_), dim3(256), 0, stream>>>(kb, vb, S);
    scan_kernel<<<dim3(B_ * H_), dim3(256), 0, stream>>>(S, td, stT);
    rstate_gn_kernel<<<dim3(B_ * H_ * NC_), dim3(256), 0, stream>>>(rb, stT, gnw, gnb, ygn);

    gemm_bt<true><<<gg, 256, 0, stream>>>(ygn, wob, out, 16384, 1024, 1024);
}

// Round 6
// 412.963 us; speedup vs baseline: 1.3406x; 1.0056x over previous
//
#include <hip/hip_runtime.h>

typedef unsigned short u16;
typedef __attribute__((ext_vector_type(4))) unsigned int u32x4;
typedef __attribute__((ext_vector_type(4))) float f32x4;
typedef __attribute__((ext_vector_type(8))) short s16x8;

#define B_ 8
#define T_ 2048
#define C_ 1024
#define H_ 16
#define HS_ 64
#define CHUNK_ 256
#define NC_ 8

union U8 { u32x4 u; u16 h[8]; };

__device__ __forceinline__ float b2f(u16 v) {
    union { unsigned int i; float f; } c; c.i = ((unsigned int)v) << 16; return c.f;
}
__device__ __forceinline__ u16 f2b(float f) {
    union { float f; unsigned int i; } c; c.f = f;
    unsigned int i = c.i;
    return (u16)((i + 0x7FFFu + ((i >> 16) & 1u)) >> 16);  // RNE
}
// fast sigmoid: v_exp_f32 + v_rcp_f32 (args here are tiny, ~0.02 — no range issues)
__device__ __forceinline__ float fsig(float z) {
    return __builtin_amdgcn_rcpf(1.f + __expf(-z));
}

// async 16B global->LDS (lds dest = wave-uniform base + lane*16)
typedef __attribute__((address_space(1))) void GV;
typedef __attribute__((address_space(3))) void LV;
__device__ __forceinline__ void glds16(const void* g, void* l) {
    __builtin_amdgcn_global_load_lds((GV*)g, (LV*)l, 16, 0, 0);
}

// ---------------- K0: f32 -> bf16 conversion of the 4 weight matrices ------
__global__ __launch_bounds__(256) void cvt4_kernel(
    const float* __restrict__ s0, const float* __restrict__ s1,
    const float* __restrict__ s2, const float* __restrict__ s3,
    u16* __restrict__ dst)
{
    int i = blockIdx.x * 256 + threadIdx.x;   // 4 * 131072 threads, 8 elems each
    int m = i >> 17;
    const float* s = (m == 0) ? s0 : (m == 1) ? s1 : (m == 2) ? s2 : s3;
    size_t j = (size_t)(i & 131071) * 8;
    f32x4 a = *reinterpret_cast<const f32x4*>(s + j);
    f32x4 b = *reinterpret_cast<const f32x4*>(s + j + 4);
    U8 o;
    #pragma unroll
    for (int k = 0; k < 4; k++) { o.h[k] = f2b(a[k]); o.h[4 + k] = f2b(b[k]); }
    *reinterpret_cast<u32x4*>(dst + (size_t)m * C_ * C_ + j) = o.u;
}

// ---------------- K1: gate + time-shift + maa mix, 8-row t-strip ------------
// Each thread: 8-channel block x 8 consecutive t. Carries g_prev in regs so
// each x row is loaded & gated exactly once (plus one boundary row per strip).
__global__ __launch_bounds__(256) void mix_kernel(
    const float* __restrict__ x, const float* __restrict__ vol,
    const float* __restrict__ Wvol, const float* __restrict__ bvol,
    const float* __restrict__ mk, const float* __restrict__ mv, const float* __restrict__ mr,
    u16* __restrict__ xk, u16* __restrict__ xv, u16* __restrict__ xr)
{
    int idx = blockIdx.x * 256 + threadIdx.x;      // B*(T/8)*(C/8) threads
    int c0 = (idx & 127) * 8;
    int bt8 = idx >> 7;
    int t0  = (bt8 & 255) * 8;
    int b   = bt8 >> 8;
    size_t rowOff = ((size_t)b * T_ + t0) * C_ + c0;

    float wv[8], bv[8], mkv[8], mvv[8], mrv[8];
    #pragma unroll
    for (int j = 0; j < 8; j += 4) {
        f32x4 a;
        a = *reinterpret_cast<const f32x4*>(Wvol + c0 + j);
        wv[j] = a[0]; wv[j+1] = a[1]; wv[j+2] = a[2]; wv[j+3] = a[3];
        a = *reinterpret_cast<const f32x4*>(bvol + c0 + j);
        bv[j] = a[0]; bv[j+1] = a[1]; bv[j+2] = a[2]; bv[j+3] = a[3];
        a = *reinterpret_cast<const f32x4*>(mk + c0 + j);
        mkv[j] = a[0]; mkv[j+1] = a[1]; mkv[j+2] = a[2]; mkv[j+3] = a[3];
        a = *reinterpret_cast<const f32x4*>(mv + c0 + j);
        mvv[j] = a[0]; mvv[j+1] = a[1]; mvv[j+2] = a[2]; mvv[j+3] = a[3];
        a = *reinterpret_cast<const f32x4*>(mr + c0 + j);
        mrv[j] = a[0]; mrv[j+1] = a[1]; mrv[j+2] = a[2]; mrv[j+3] = a[3];
    }

    const float* volb = vol + (size_t)b * T_;
    float gp[8];
    if (t0 == 0) {
        #pragma unroll
        for (int j = 0; j < 8; j++) gp[j] = 0.f;
    } else {
        float vp = volb[t0 - 1];
        #pragma unroll
        for (int j = 0; j < 8; j += 4) {
            f32x4 a = *reinterpret_cast<const f32x4*>(x + rowOff - C_ + j);
            gp[j]   = a[0] * fsig(vp * wv[j]   + bv[j]);
            gp[j+1] = a[1] * fsig(vp * wv[j+1] + bv[j+1]);
            gp[j+2] = a[2] * fsig(vp * wv[j+2] + bv[j+2]);
            gp[j+3] = a[3] * fsig(vp * wv[j+3] + bv[j+3]);
        }
    }

    #pragma unroll
    for (int s = 0; s < 8; s++) {
        float vc = volb[t0 + s];
        size_t off = rowOff + (size_t)s * C_;
        float g[8];
        #pragma unroll
        for (int j = 0; j < 8; j += 4) {
            f32x4 a = *reinterpret_cast<const f32x4*>(x + off + j);
            g[j]   = a[0] * fsig(vc * wv[j]   + bv[j]);
            g[j+1] = a[1] * fsig(vc * wv[j+1] + bv[j+1]);
            g[j+2] = a[2] * fsig(vc * wv[j+2] + bv[j+2]);
            g[j+3] = a[3] * fsig(vc * wv[j+3] + bv[j+3]);
        }
        U8 ok, ov, orr;
        #pragma unroll
        for (int j = 0; j < 8; j++) {
            float xx = gp[j] - g[j];
            ok.h[j]  = f2b(g[j] + xx * mkv[j]);
            ov.h[j]  = f2b(g[j] + xx * mvv[j]);
            orr.h[j] = f2b(g[j] + xx * mrv[j]);
            gp[j] = g[j];
        }
        *reinterpret_cast<u32x4*>(xk + off) = ok.u;
        *reinterpret_cast<u32x4*>(xv + off) = ov.u;
        *reinterpret_cast<u32x4*>(xr + off) = orr.u;
    }
}

// ---------------- K2: C = A @ W^T  (BK=64: half the barrier drains) ---------
#define BM_ 128
#define BN_ 128
#define BK_ 64

template<bool F32OUT>
__global__ __launch_bounds__(256) void gemm_bt(
    const u16* __restrict__ A, const u16* __restrict__ W,
    void* __restrict__ Cc, int M, int N, int K)
{
    __shared__ __align__(16) u16 Ash[BM_ * BK_];
    __shared__ __align__(16) u16 Bsh[BN_ * BK_];
    int tid  = threadIdx.x;
    int lane = tid & 63;
    int wave = tid >> 6;
    int wm = (wave >> 1) * 64;
    int wn = (wave & 1) * 64;
    int r16 = lane & 15;
    int quad = lane >> 4;
    int bm = blockIdx.x, bn = blockIdx.y;

    f32x4 acc[4][4];
    #pragma unroll
    for (int mi = 0; mi < 4; mi++)
        #pragma unroll
        for (int ni = 0; ni < 4; ni++)
            acc[mi][ni] = f32x4{0.f, 0.f, 0.f, 0.f};

    const u16* Ab = A + (size_t)bm * BM_ * K;
    const u16* Wb = W + (size_t)bn * BN_ * K;

    size_t gOf[4];
    u16 *ldA[4], *ldB[4];
    #pragma unroll
    for (int i = 0; i < 4; i++) {
        int p = (i * 4 + wave) * 64 + lane;
        int row = p >> 3;
        int ccG = (p & 7) ^ (row & 7);
        gOf[i] = (size_t)row * K + ccG * 8;
        ldA[i] = &Ash[(i * 4 + wave) * 512];
        ldB[i] = &Bsh[(i * 4 + wave) * 512];
    }

    int faOff[2][4], fbOff[2][4];
    #pragma unroll
    for (int ks = 0; ks < 2; ks++) {
        #pragma unroll
        for (int i = 0; i < 4; i++) {
            int rowA = wm + i * 16 + r16;
            faOff[ks][i] = rowA * BK_ + (((ks * 4 + quad) ^ (rowA & 7)) * 8);
            int rowB = wn + i * 16 + r16;
            fbOff[ks][i] = rowB * BK_ + (((ks * 4 + quad) ^ (rowB & 7)) * 8);
        }
    }

    for (int k0 = 0; k0 < K; k0 += BK_) {
        #pragma unroll
        for (int i = 0; i < 4; i++) {
            glds16(Ab + gOf[i] + k0, ldA[i]);
            glds16(Wb + gOf[i] + k0, ldB[i]);
        }
        __syncthreads();
        #pragma unroll
        for (int ks = 0; ks < 2; ks++) {
            s16x8 fa[4], fb[4];
            #pragma unroll
            for (int mi = 0; mi < 4; mi++)
                fa[mi] = *reinterpret_cast<const s16x8*>(&Ash[faOff[ks][mi]]);
            #pragma unroll
            for (int ni = 0; ni < 4; ni++)
                fb[ni] = *reinterpret_cast<const s16x8*>(&Bsh[fbOff[ks][ni]]);
            #pragma unroll
            for (int mi = 0; mi < 4; mi++)
                #pragma unroll
                for (int ni = 0; ni < 4; ni++)
                    acc[mi][ni] = __builtin_amdgcn_mfma_f32_16x16x32_bf16(fa[mi], fb[ni], acc[mi][ni], 0, 0, 0);
        }
        __syncthreads();
    }

    #pragma unroll
    for (int mi = 0; mi < 4; mi++) {
        int row0 = bm * BM_ + wm + mi * 16 + quad * 4;
        #pragma unroll
        for (int ni = 0; ni < 4; ni++) {
            int col = bn * BN_ + wn + ni * 16 + r16;
            #pragma unroll
            for (int i = 0; i < 4; i++) {
                if (F32OUT)
                    ((float*)Cc)[(size_t)(row0 + i) * N + col] = acc[mi][ni][i];
                else
                    ((u16*)Cc)[(size_t)(row0 + i) * N + col] = f2b(acc[mi][ni][i]);
            }
        }
    }
}

// ---------------- K3a: P = v^T k per (b,h,chunk) via MFMA -------------------
__global__ __launch_bounds__(256) void kvouter_kernel(
    const u16* __restrict__ k, const u16* __restrict__ v, float* __restrict__ S)
{
    int blk = blockIdx.x;          // bh*NC + j
    int j  = blk & (NC_ - 1);
    int bh = blk >> 3;
    int h = bh & (H_ - 1);
    int b = bh >> 4;
    __shared__ __align__(16) u16 kT[HS_ * 136];
    __shared__ __align__(16) u16 vT[HS_ * 136];
    int tid = threadIdx.x, lane = tid & 63, wave = tid >> 6;
    int r16 = lane & 15, quad = lane >> 4;
    int n0 = (wave >> 1) * 32, m0 = (wave & 1) * 32;
    int a = tid & 7, c8 = a * 8;

    f32x4 acc[2][2];
    #pragma unroll
    for (int ni = 0; ni < 2; ni++)
        #pragma unroll
        for (int mi = 0; mi < 2; mi++)
            acc[ni][mi] = f32x4{0.f, 0.f, 0.f, 0.f};

    size_t base = ((size_t)(b * T_ + j * CHUNK_)) * C_ + h * HS_;
    #pragma unroll
    for (int half = 0; half < 2; half++) {
        size_t hb = base + (size_t)half * 128 * C_;
        #pragma unroll
        for (int i = 0; i < 4; i++) {
            int s = (tid + i * 256) >> 3;
            U8 uk, uv;
            uk.u = *reinterpret_cast<const u32x4*>(k + hb + (size_t)s * C_ + c8);
            uv.u = *reinterpret_cast<const u32x4*>(v + hb + (size_t)s * C_ + c8);
            #pragma unroll
            for (int jj = 0; jj < 8; jj++) {
                int w = jj ^ a;
                kT[(c8 + w) * 136 + s] = uk.h[w];
                vT[(c8 + w) * 136 + s] = uv.h[w];
            }
        }
        __syncthreads();
        #pragma unroll
        for (int ks = 0; ks < 4; ks++) {
            s16x8 fa[2], fb[2];
            #pragma unroll
            for (int ni = 0; ni < 2; ni++)
                fa[ni] = *reinterpret_cast<const s16x8*>(
                    &vT[(n0 + ni * 16 + r16) * 136 + ks * 32 + quad * 8]);
            #pragma unroll
            for (int mi = 0; mi < 2; mi++)
                fb[mi] = *reinterpret_cast<const s16x8*>(
                    &kT[(m0 + mi * 16 + r16) * 136 + ks * 32 + quad * 8]);
            #pragma unroll
            for (int ni = 0; ni < 2; ni++)
                #pragma unroll
                for (int mi = 0; mi < 2; mi++)
                    acc[ni][mi] = __builtin_amdgcn_mfma_f32_16x16x32_bf16(fa[ni], fb[mi], acc[ni][mi], 0, 0, 0);
        }
        __syncthreads();
    }
    float* out = S + (size_t)blk * (HS_ * HS_);
    #pragma unroll
    for (int ni = 0; ni < 2; ni++)
        #pragma unroll
        for (int mi = 0; mi < 2; mi++)
            #pragma unroll
            for (int i = 0; i < 4; i++)
                out[(n0 + ni * 16 + quad * 4 + i) * HS_ + m0 + mi * 16 + r16] = acc[ni][mi][i];
}

// ---------------- K3b: decay scan (elementwise in (n,m) layout) -------------
__global__ __launch_bounds__(256) void scan_kernel(
    const float* __restrict__ S, const float* __restrict__ td, u16* __restrict__ stT)
{
    int bh = blockIdx.x;
    int h = bh & (H_ - 1);
    float w = expf(-expf(td[h]));
    int tid = threadIdx.x;
    float st[16];
    #pragma unroll
    for (int i = 0; i < 16; i++) st[i] = 0.f;
    for (int c = 0; c < NC_; c++) {
        size_t off = ((size_t)(bh * NC_ + c)) * 4096 + tid * 16;
        const float* sp = S + off;
        #pragma unroll
        for (int i = 0; i < 16; i++) st[i] = w * (st[i] + sp[i]);
        U8 o0, o1;
        #pragma unroll
        for (int i = 0; i < 8; i++) { o0.h[i] = f2b(st[i]); o1.h[i] = f2b(st[8 + i]); }
        *reinterpret_cast<u32x4*>(stT + off)     = o0.u;
        *reinterpret_cast<u32x4*>(stT + off + 8) = o1.u;
    }
}

// ---------------- K3c: y = r @ state (MFMA), fused GroupNorm ----------------
__global__ __launch_bounds__(256) void rstate_gn_kernel(
    const u16* __restrict__ r, const u16* __restrict__ stT,
    const float* __restrict__ gnw, const float* __restrict__ gnb, u16* __restrict__ ygn)
{
    int blk = blockIdx.x;      // bh*NC + c
    int c  = blk & (NC_ - 1);
    int bh = blk >> 3;
    int h = bh & (H_ - 1);
    int b = bh >> 4;
    __shared__ __align__(16) u16 sT[HS_ * 72];   // pitch 72 u16
    int tid = threadIdx.x, lane = tid & 63, wave = tid >> 6;
    int r16 = lane & 15, quad = lane >> 4;

    const u16* sg = stT + (size_t)blk * (HS_ * HS_);
    for (int i = tid; i < 512; i += 256) {
        int n = i >> 3, c8 = (i & 7) * 8;
        *reinterpret_cast<u32x4*>(&sT[n * 72 + c8]) =
            *reinterpret_cast<const u32x4*>(sg + n * HS_ + c8);
    }
    __syncthreads();

    size_t rowBase = (size_t)(b * T_ + c * CHUNK_ + wave * 64);
    f32x4 acc[4][4];
    #pragma unroll
    for (int mi = 0; mi < 4; mi++)
        #pragma unroll
        for (int ni = 0; ni < 4; ni++)
            acc[mi][ni] = f32x4{0.f, 0.f, 0.f, 0.f};

    #pragma unroll
    for (int ks = 0; ks < 2; ks++) {
        int kb = ks * 32 + quad * 8;
        s16x8 fa[4], fb[4];
        #pragma unroll
        for (int mi = 0; mi < 4; mi++)
            fa[mi] = *reinterpret_cast<const s16x8*>(
                r + (rowBase + mi * 16 + r16) * C_ + h * HS_ + kb);
        #pragma unroll
        for (int ni = 0; ni < 4; ni++)
            fb[ni] = *reinterpret_cast<const s16x8*>(&sT[(ni * 16 + r16) * 72 + kb]);
        #pragma unroll
        for (int mi = 0; mi < 4; mi++)
            #pragma unroll
            for (int ni = 0; ni < 4; ni++)
                acc[mi][ni] = __builtin_amdgcn_mfma_f32_16x16x32_bf16(fa[mi], fb[ni], acc[mi][ni], 0, 0, 0);
    }

    float gwv[4], gbv[4];
    #pragma unroll
    for (int ni = 0; ni < 4; ni++) {
        int col = ni * 16 + r16;
        gwv[ni] = gnw[h * HS_ + col];
        gbv[ni] = gnb[h * HS_ + col];
    }
    #pragma unroll
    for (int mi = 0; mi < 4; mi++) {
        float s1[4], s2[4];
        #pragma unroll
        for (int i = 0; i < 4; i++) {
            float s = 0.f, ss = 0.f;
            #pragma unroll
            for (int ni = 0; ni < 4; ni++) {
                float v = acc[mi][ni][i];
                s += v; ss += v * v;
            }
            s1[i] = s; s2[i] = ss;
        }
        #pragma unroll
        for (int d = 1; d < 16; d <<= 1) {
            #pragma unroll
            for (int i = 0; i < 4; i++) {
                s1[i] += __shfl_xor(s1[i], d);
                s2[i] += __shfl_xor(s2[i], d);
            }
        }
        #pragma unroll
        for (int i = 0; i < 4; i++) {
            float mu = s1[i] * (1.f / 64.f);
            float var = s2[i] * (1.f / 64.f) - mu * mu;
            float sc = rsqrtf(var + 1e-5f);
            size_t ob = (rowBase + mi * 16 + quad * 4 + i) * C_ + h * HS_;
            #pragma unroll
            for (int ni = 0; ni < 4; ni++)
                ygn[ob + ni * 16 + r16] = f2b((acc[mi][ni][i] - mu) * sc * gwv[ni] + gbv[ni]);
        }
    }
}

// ---------------------------------------------------------------------------
extern "C" void kernel_launch(void* const* d_in, const int* in_sizes, int n_in,
                              void* d_out, int out_size, void* d_ws, size_t ws_size,
                              hipStream_t stream) {
    const float* x    = (const float*)d_in[0];
    const float* vol  = (const float*)d_in[1];
    const float* Wvol = (const float*)d_in[2];
    const float* bvol = (const float*)d_in[3];
    const float* mk   = (const float*)d_in[4];
    const float* mv   = (const float*)d_in[5];
    const float* mr   = (const float*)d_in[6];
    const float* td   = (const float*)d_in[7];
    const float* Wk   = (const float*)d_in[8];
    const float* Wv   = (const float*)d_in[9];
    const float* Wr   = (const float*)d_in[10];
    const float* Wo   = (const float*)d_in[11];
    const float* gnw  = (const float*)d_in[12];
    const float* gnb  = (const float*)d_in[13];
    float* out = (float*)d_out;

    char* ws = (char*)d_ws;
    const size_t SLOT = (size_t)B_ * T_ * C_ * 2;   // 33,554,432 B
    // s0: xr -> kb -> ygn ; s1: xk -> vb ; s2: xv -> S(f32) + stT(bf16) ; s3: rb
    u16* xr = (u16*)(ws + 0 * SLOT);
    u16* xk = (u16*)(ws + 1 * SLOT);
    u16* xv = (u16*)(ws + 2 * SLOT);
    u16* rb = (u16*)(ws + 3 * SLOT);
    u16* kb = (u16*)(ws + 0 * SLOT);
    u16* vb = (u16*)(ws + 1 * SLOT);
    float* S   = (float*)(ws + 2 * SLOT);                 // 16.8 MB
    u16*   stT = (u16*)  (ws + 2 * SLOT + SLOT / 2);      // 8.4 MB
    u16* ygn = (u16*)(ws + 0 * SLOT);
    u16* wtb = (u16*)(ws + 4 * SLOT);                     // 4 bf16 weight mats
    u16* wrb = wtb;
    u16* wkb = wrb + (size_t)C_ * C_;
    u16* wvb = wkb + (size_t)C_ * C_;
    u16* wob = wvb + (size_t)C_ * C_;

    cvt4_kernel<<<dim3(4 * (C_ * C_ / 8) / 256), dim3(256), 0, stream>>>(Wr, Wk, Wv, Wo, wtb);

    // B*(T/8)*(C/8) threads = 262144 -> 1024 blocks
    mix_kernel<<<dim3(1024), dim3(256), 0, stream>>>(
        x, vol, Wvol, bvol, mk, mv, mr, xk, xv, xr);

    dim3 gg(16384 / BM_, 1024 / BN_);  // (128, 8)
    gemm_bt<false><<<gg, 256, 0, stream>>>(xr, wrb, rb, 16384, 1024, 1024);
    gemm_bt<false><<<gg, 256, 0, stream>>>(xk, wkb, kb, 16384, 1024, 1024);
    gemm_bt<false><<<gg, 256, 0, stream>>>(xv, wvb, vb, 16384, 1024, 1024);

    kvouter_kernel<<<dim3(B_ * H_ * NC_), dim3(256), 0, stream>>>(kb, vb, S);
    scan_kernel<<<dim3(B_ * H_), dim3(256), 0, stream>>>(S, td, stT);
    rstate_gn_kernel<<<dim3(B_ * H_ * NC_), dim3(256), 0, stream>>>(rb, stT, gnw, gnb, ygn);

    gemm_bt<true><<<gg, 256, 0, stream>>>(ygn, wob, out, 16384, 1024, 1024);
}